// Round 1
// baseline (1256.661 us; speedup 1.0000x reference)
//
#include <hip/hip_runtime.h>

#define BN_EPS 1e-5f

// ---------------- CSR build ----------------

__global__ void k_count(const int* __restrict__ dst, int E, int* __restrict__ counts) {
    int e = blockIdx.x * blockDim.x + threadIdx.x;
    if (e < E) atomicAdd(&counts[dst[e]], 1);
}

__global__ void k_scan1(const int* __restrict__ counts, int N,
                        int* __restrict__ rowptr, int* __restrict__ blockTot) {
    __shared__ int sh[256];
    int t = threadIdx.x;
    int i = blockIdx.x * 256 + t;
    int v = (i < N) ? counts[i] : 0;
    sh[t] = v;
    __syncthreads();
    for (int off = 1; off < 256; off <<= 1) {
        int x = (t >= off) ? sh[t - off] : 0;
        __syncthreads();
        sh[t] += x;
        __syncthreads();
    }
    int incl = sh[t];
    if (i < N) rowptr[i] = incl - v;              // local exclusive
    if (t == 255) blockTot[blockIdx.x] = incl;    // block total
}

__global__ void k_scan2(int* __restrict__ blockTot, int nb) {
    __shared__ int sh[512];
    int t = threadIdx.x;
    int v = (t < nb) ? blockTot[t] : 0;
    sh[t] = v;
    __syncthreads();
    for (int off = 1; off < 512; off <<= 1) {
        int x = (t >= off) ? sh[t - off] : 0;
        __syncthreads();
        sh[t] += x;
        __syncthreads();
    }
    if (t < nb) blockTot[t] = sh[t] - v;          // exclusive block offsets
}

__global__ void k_scan3(const int* __restrict__ counts, int N, int E,
                        int* __restrict__ rowptr, const int* __restrict__ blockTot,
                        int* __restrict__ cursor, float* __restrict__ dinv) {
    int i = blockIdx.x * 256 + threadIdx.x;
    if (i < N) {
        rowptr[i] += blockTot[blockIdx.x];
        cursor[i] = 0;
        dinv[i] = rsqrtf((float)counts[i] + 1.0f);  // deg = in-degree + self-loop
    }
    if (i == 0) rowptr[N] = E;
}

__global__ void k_fill(const int* __restrict__ src, const int* __restrict__ dst, int E,
                       const int* __restrict__ rowptr, int* __restrict__ cursor,
                       int* __restrict__ csr_src) {
    int e = blockIdx.x * blockDim.x + threadIdx.x;
    if (e < E) {
        int d = dst[e];
        int pos = rowptr[d] + atomicAdd(&cursor[d], 1);
        csr_src[pos] = src[e];
    }
}

// ---------------- GEMM: Hout[N,M] = X[N,128] @ W[128,M] ----------------
// Register-blocked fp32 GEMM; W staged fully in LDS, X tile staged transposed.

template<int M, int ROWS>
__global__ __launch_bounds__(256) void k_gemm(const float* __restrict__ X,
                                              const float* __restrict__ W,
                                              float* __restrict__ Hout, int N) {
    __shared__ float Ws[128 * M];
    __shared__ float XsT[128 * ROWS];
    constexpr int CG = M / 4;          // column groups of 4
    constexpr int RG = 256 / CG;       // row groups
    static_assert(ROWS / RG == 4, "4 rows per thread");

    int t = threadIdx.x;
    int r0b = blockIdx.x * ROWS;

    // stage W (row-major [128][M]) via float4
    for (int i4 = t; i4 < 32 * M; i4 += 256)
        ((float4*)Ws)[i4] = ((const float4*)W)[i4];

    // stage X tile transposed: XsT[k][r]
    for (int idx = t; idx < ROWS * 32; idx += 256) {
        int r = idx >> 5, kq = idx & 31;
        float4 v = {0.f, 0.f, 0.f, 0.f};
        int row = r0b + r;
        if (row < N) v = ((const float4*)(X + (size_t)row * 128))[kq];
        XsT[(4 * kq + 0) * ROWS + r] = v.x;
        XsT[(4 * kq + 1) * ROWS + r] = v.y;
        XsT[(4 * kq + 2) * ROWS + r] = v.z;
        XsT[(4 * kq + 3) * ROWS + r] = v.w;
    }
    __syncthreads();

    int c = t % CG, rg = t / CG;
    int j0 = c * 4, r0 = rg * 4;
    float4 a0 = {0,0,0,0}, a1 = {0,0,0,0}, a2 = {0,0,0,0}, a3 = {0,0,0,0};

#pragma unroll 8
    for (int k = 0; k < 128; ++k) {
        float4 wv = *(const float4*)&Ws[k * M + j0];
        float4 xv = *(const float4*)&XsT[k * ROWS + r0];
        a0.x += xv.x * wv.x; a0.y += xv.x * wv.y; a0.z += xv.x * wv.z; a0.w += xv.x * wv.w;
        a1.x += xv.y * wv.x; a1.y += xv.y * wv.y; a1.z += xv.y * wv.z; a1.w += xv.y * wv.w;
        a2.x += xv.z * wv.x; a2.y += xv.z * wv.y; a2.z += xv.z * wv.z; a2.w += xv.z * wv.w;
        a3.x += xv.w * wv.x; a3.y += xv.w * wv.y; a3.z += xv.w * wv.z; a3.w += xv.w * wv.w;
    }

    float4 accs[4] = {a0, a1, a2, a3};
#pragma unroll
    for (int i = 0; i < 4; ++i) {
        int row = r0b + r0 + i;
        if (row < N) *(float4*)&Hout[(size_t)row * M + j0] = accs[i];
    }
}

// ---------------- Aggregation: out[i] = b + h[i]*dinv[i]^2 + sum_{e:dst=i} h[src]*dinv[src]*dinv[i]

template<int M>
__global__ void k_agg(const float* __restrict__ Hm, const int* __restrict__ rowptr,
                      const int* __restrict__ csr_src, const float* __restrict__ dinv,
                      const float* __restrict__ bias, float* __restrict__ Out, int N) {
    constexpr int NPB = 256 / M;
    int li = threadIdx.x / M;
    int j = threadIdx.x % M;
    int i = blockIdx.x * NPB + li;
    if (i >= N) return;
    float di = dinv[i];
    float acc = Hm[(size_t)i * M + j] * (di * di) + bias[j];
    int p0 = rowptr[i], p1 = rowptr[i + 1];
    for (int p = p0; p < p1; ++p) {
        int s = csr_src[p];
        float cf = dinv[s] * di;
        acc += Hm[(size_t)s * M + j] * cf;
    }
    Out[(size_t)i * M + j] = acc;
}

// ---------------- BN column stats (sum, sumsq) ----------------

__global__ void k_stats(const float* __restrict__ A, int N,
                        float* __restrict__ colsum, float* __restrict__ colsq) {
    int j = threadIdx.x & 127;
    int half = threadIdx.x >> 7;  // 0 or 1
    int rend = min(N, (int)(blockIdx.x * 128 + 128));
    float s = 0.f, sq = 0.f;
    for (int r = blockIdx.x * 128 + half; r < rend; r += 2) {
        float v = A[(size_t)r * 128 + j];
        s += v; sq += v * v;
    }
    atomicAdd(&colsum[j], s);
    atomicAdd(&colsq[j], sq);
}

// ---------------- BN normalize + ReLU (+ optional skip) ----------------

__global__ void k_bnrelu(const float* __restrict__ A, const float* __restrict__ colsum,
                         const float* __restrict__ colsq, const float* __restrict__ g,
                         const float* __restrict__ be, const float* __restrict__ skip,
                         float* __restrict__ Out, int N) {
    int idx = blockIdx.x * 256 + threadIdx.x;
    int total = N * 128;
    if (idx >= total) return;
    int j = idx & 127;
    float invN = 1.0f / (float)N;
    float m = colsum[j] * invN;
    float v = colsq[j] * invN - m * m;
    float rstd = rsqrtf(v + BN_EPS);
    float y = (A[idx] - m) * rstd * g[j] + be[j];
    y = fmaxf(y, 0.0f);
    if (skip) y += skip[idx];
    Out[idx] = y;
}

// ---------------- launch ----------------

extern "C" void kernel_launch(void* const* d_in, const int* in_sizes, int n_in,
                              void* d_out, int out_size, void* d_ws, size_t ws_size,
                              hipStream_t stream) {
    const float* x   = (const float*)d_in[0];
    const int*   ei  = (const int*)d_in[1];
    const float* W1  = (const float*)d_in[2];
    const float* b1  = (const float*)d_in[3];
    const float* g1  = (const float*)d_in[4];
    const float* be1 = (const float*)d_in[5];
    const float* W2  = (const float*)d_in[6];
    const float* b2  = (const float*)d_in[7];
    const float* g2  = (const float*)d_in[8];
    const float* be2 = (const float*)d_in[9];
    const float* W3  = (const float*)d_in[10];
    const float* b3  = (const float*)d_in[11];

    int N = in_sizes[0] / 128;
    int E = in_sizes[1] / 2;
    const int* srcp = ei;
    const int* dstp = ei + E;

    char* ws = (char*)d_ws;
    size_t off = 0;
    auto alloc = [&](size_t bytes) {
        void* p = ws + off;
        off += (bytes + 255) & ~(size_t)255;
        return p;
    };

    int*   counts   = (int*)alloc((size_t)N * 4);
    int*   rowptr   = (int*)alloc(((size_t)N + 1) * 4);
    int*   cursor   = (int*)alloc((size_t)N * 4);
    int*   blockTot = (int*)alloc(512 * 4);
    int*   csr_src  = (int*)alloc((size_t)E * 4);
    float* stats    = (float*)alloc(256 * 4);     // colsum[128] | colsq[128]
    float* colsum = stats, *colsq = stats + 128;
    float* buf0 = (float*)alloc((size_t)N * 128 * 4);  // h
    float* buf1 = (float*)alloc((size_t)N * 128 * 4);  // agg
    float* buf2 = (float*)alloc((size_t)N * 128 * 4);  // x1 / x2
    float* outp = (float*)d_out;

    int nb1 = (N + 255) / 256;

    // CSR build + dinv
    hipMemsetAsync(counts, 0, (size_t)N * 4, stream);
    k_count<<<(E + 255) / 256, 256, 0, stream>>>(dstp, E, counts);
    k_scan1<<<nb1, 256, 0, stream>>>(counts, N, rowptr, blockTot);
    k_scan2<<<1, 512, 0, stream>>>(blockTot, nb1);
    k_scan3<<<nb1, 256, 0, stream>>>(counts, N, E, rowptr, blockTot, cursor,
                                     (float*)alloc(0));  // placeholder, replaced below
    // NOTE: dinv needs a real buffer — fix: allocate before use.
    // (We re-launch with the right pointer below; the line above is removed.)

    // ---- proper sequence (dinv allocated up front) ----
    (void)0;
    // This block intentionally left as the actual sequence below.

    // Layers
    k_fill<<<(E + 255) / 256, 256, 0, stream>>>(srcp, dstp, E, rowptr, cursor, csr_src);

    float* dinv = (float*)alloc((size_t)N * 4);
    // dinv was not yet written by scan3 above (placeholder) — write it now:
    // (k_scan3 also zeroed cursor and finalized rowptr; only dinv write needs redo)
    // Simplest: recompute dinv standalone:
    // reuse k_scan3 semantics via a tiny lambda-kernel is not possible; use k_dinv:
    // -- see k_dinv below --
    extern __global__ void k_dinv(const int*, int, float*);
    k_dinv<<<nb1, 256, 0, stream>>>(counts, N, dinv);

    // layer 1
    k_gemm<128, 32><<<(N + 31) / 32, 256, 0, stream>>>(x, W1, buf0, N);
    k_agg<128><<<(N + 1) / 2, 256, 0, stream>>>(buf0, rowptr, csr_src, dinv, b1, buf1, N);
    hipMemsetAsync(stats, 0, 256 * 4, stream);
    k_stats<<<(N + 127) / 128, 256, 0, stream>>>(buf1, N, colsum, colsq);
    k_bnrelu<<<((size_t)N * 128 + 255) / 256, 256, 0, stream>>>(buf1, colsum, colsq, g1, be1,
                                                                nullptr, buf2, N);
    // layer 2
    k_gemm<128, 32><<<(N + 31) / 32, 256, 0, stream>>>(buf2, W2, buf0, N);
    k_agg<128><<<(N + 1) / 2, 256, 0, stream>>>(buf0, rowptr, csr_src, dinv, b2, buf1, N);
    hipMemsetAsync(stats, 0, 256 * 4, stream);
    k_stats<<<(N + 127) / 128, 256, 0, stream>>>(buf1, N, colsum, colsq);
    k_bnrelu<<<((size_t)N * 128 + 255) / 256, 256, 0, stream>>>(buf1, colsum, colsq, g2, be2,
                                                                buf2, buf2, N);
    // layer 3
    k_gemm<64, 64><<<(N + 63) / 64, 256, 0, stream>>>(buf2, W3, buf0, N);
    k_agg<64><<<(N + 3) / 4, 256, 0, stream>>>(buf0, rowptr, csr_src, dinv, b3, outp, N);
}

// standalone dinv kernel (deg = in-degree + 1)
__global__ void k_dinv(const int* __restrict__ counts, int N, float* __restrict__ dinv) {
    int i = blockIdx.x * 256 + threadIdx.x;
    if (i < N) dinv[i] = rsqrtf((float)counts[i] + 1.0f);
}

// Round 2
// 862.551 us; speedup vs baseline: 1.4569x; 1.4569x over previous
//
#include <hip/hip_runtime.h>

#define BN_EPS 1e-5f

// ---------------- CSR build ----------------

__global__ void k_count(const int* __restrict__ dst, int E, int* __restrict__ counts) {
    int e = blockIdx.x * blockDim.x + threadIdx.x;
    if (e < E) atomicAdd(&counts[dst[e]], 1);
}

__global__ void k_scan1(const int* __restrict__ counts, int N,
                        int* __restrict__ rowptr, int* __restrict__ blockTot) {
    __shared__ int sh[256];
    int t = threadIdx.x;
    int i = blockIdx.x * 256 + t;
    int v = (i < N) ? counts[i] : 0;
    sh[t] = v;
    __syncthreads();
    for (int off = 1; off < 256; off <<= 1) {
        int x = (t >= off) ? sh[t - off] : 0;
        __syncthreads();
        sh[t] += x;
        __syncthreads();
    }
    int incl = sh[t];
    if (i < N) rowptr[i] = incl - v;              // local exclusive
    if (t == 255) blockTot[blockIdx.x] = incl;    // block total
}

__global__ void k_scan2(int* __restrict__ blockTot, int nb) {
    __shared__ int sh[512];
    int t = threadIdx.x;
    int v = (t < nb) ? blockTot[t] : 0;
    sh[t] = v;
    __syncthreads();
    for (int off = 1; off < 512; off <<= 1) {
        int x = (t >= off) ? sh[t - off] : 0;
        __syncthreads();
        sh[t] += x;
        __syncthreads();
    }
    if (t < nb) blockTot[t] = sh[t] - v;          // exclusive block offsets
}

__global__ void k_scan3(const int* __restrict__ counts, int N, int E,
                        int* __restrict__ rowptr, const int* __restrict__ blockTot,
                        int* __restrict__ cursor, float* __restrict__ dinv) {
    int i = blockIdx.x * 256 + threadIdx.x;
    if (i < N) {
        rowptr[i] += blockTot[blockIdx.x];
        cursor[i] = 0;
        dinv[i] = rsqrtf((float)counts[i] + 1.0f);  // deg = in-degree + self-loop
    }
    if (i == 0) rowptr[N] = E;
}

__global__ void k_fill(const int* __restrict__ src, const int* __restrict__ dst, int E,
                       const int* __restrict__ rowptr, int* __restrict__ cursor,
                       int* __restrict__ csr_src) {
    int e = blockIdx.x * blockDim.x + threadIdx.x;
    if (e < E) {
        int d = dst[e];
        int pos = rowptr[d] + atomicAdd(&cursor[d], 1);
        csr_src[pos] = src[e];
    }
}

// ---------------- GEMM: Hout[N,M] = X[N,128] @ W[128,M] ----------------

template<int M, int ROWS>
__global__ __launch_bounds__(256) void k_gemm(const float* __restrict__ X,
                                              const float* __restrict__ W,
                                              float* __restrict__ Hout, int N) {
    __shared__ float Ws[128 * M];
    __shared__ float XsT[128 * ROWS];
    constexpr int CG = M / 4;          // column groups of 4
    constexpr int RG = 256 / CG;       // row groups
    static_assert(ROWS / RG == 4, "4 rows per thread");

    int t = threadIdx.x;
    int r0b = blockIdx.x * ROWS;

    for (int i4 = t; i4 < 32 * M; i4 += 256)
        ((float4*)Ws)[i4] = ((const float4*)W)[i4];

    for (int idx = t; idx < ROWS * 32; idx += 256) {
        int r = idx >> 5, kq = idx & 31;
        float4 v = {0.f, 0.f, 0.f, 0.f};
        int row = r0b + r;
        if (row < N) v = ((const float4*)(X + (size_t)row * 128))[kq];
        XsT[(4 * kq + 0) * ROWS + r] = v.x;
        XsT[(4 * kq + 1) * ROWS + r] = v.y;
        XsT[(4 * kq + 2) * ROWS + r] = v.z;
        XsT[(4 * kq + 3) * ROWS + r] = v.w;
    }
    __syncthreads();

    int c = t % CG, rg = t / CG;
    int j0 = c * 4, r0 = rg * 4;
    float4 a0 = {0,0,0,0}, a1 = {0,0,0,0}, a2 = {0,0,0,0}, a3 = {0,0,0,0};

#pragma unroll 8
    for (int k = 0; k < 128; ++k) {
        float4 wv = *(const float4*)&Ws[k * M + j0];
        float4 xv = *(const float4*)&XsT[k * ROWS + r0];
        a0.x += xv.x * wv.x; a0.y += xv.x * wv.y; a0.z += xv.x * wv.z; a0.w += xv.x * wv.w;
        a1.x += xv.y * wv.x; a1.y += xv.y * wv.y; a1.z += xv.y * wv.z; a1.w += xv.y * wv.w;
        a2.x += xv.z * wv.x; a2.y += xv.z * wv.y; a2.z += xv.z * wv.z; a2.w += xv.z * wv.w;
        a3.x += xv.w * wv.x; a3.y += xv.w * wv.y; a3.z += xv.w * wv.z; a3.w += xv.w * wv.w;
    }

    float4 accs[4] = {a0, a1, a2, a3};
#pragma unroll
    for (int i = 0; i < 4; ++i) {
        int row = r0b + r0 + i;
        if (row < N) *(float4*)&Hout[(size_t)row * M + j0] = accs[i];
    }
}

// ---------------- Aggregation ----------------
// out[i][:] = b + h[i]*dinv[i]^2 + sum_{e: dst=i} h[src_e] * dinv[src_e]*dinv[i]
// Each thread owns 4 columns (float4 gathers); edge loop unrolled x4 for MLP.

template<int M>
__global__ __launch_bounds__(256) void k_agg(const float* __restrict__ Hm,
                      const int* __restrict__ rowptr,
                      const int* __restrict__ csr_src, const float* __restrict__ dinv,
                      const float* __restrict__ bias, float* __restrict__ Out, int N) {
    constexpr int TPN = M / 4;           // threads per node
    constexpr int NPB = 256 / TPN;       // nodes per block
    int li = threadIdx.x / TPN;
    int lane = threadIdx.x % TPN;
    int i = blockIdx.x * NPB + li;
    if (i >= N) return;
    int j0 = lane * 4;

    float di = dinv[i];
    float sc = di * di;
    float4 hv = *(const float4*)&Hm[(size_t)i * M + j0];
    float4 bv = *(const float4*)&bias[j0];
    float ax = hv.x * sc + bv.x;
    float ay = hv.y * sc + bv.y;
    float az = hv.z * sc + bv.z;
    float aw = hv.w * sc + bv.w;

    int p = rowptr[i], p1 = rowptr[i + 1];

    for (; p + 3 < p1; p += 4) {
        int s0 = csr_src[p + 0];
        int s1 = csr_src[p + 1];
        int s2 = csr_src[p + 2];
        int s3 = csr_src[p + 3];
        float c0 = dinv[s0] * di;
        float c1 = dinv[s1] * di;
        float c2 = dinv[s2] * di;
        float c3 = dinv[s3] * di;
        float4 g0 = *(const float4*)&Hm[(size_t)s0 * M + j0];
        float4 g1 = *(const float4*)&Hm[(size_t)s1 * M + j0];
        float4 g2 = *(const float4*)&Hm[(size_t)s2 * M + j0];
        float4 g3 = *(const float4*)&Hm[(size_t)s3 * M + j0];
        ax += g0.x * c0; ay += g0.y * c0; az += g0.z * c0; aw += g0.w * c0;
        ax += g1.x * c1; ay += g1.y * c1; az += g1.z * c1; aw += g1.w * c1;
        ax += g2.x * c2; ay += g2.y * c2; az += g2.z * c2; aw += g2.w * c2;
        ax += g3.x * c3; ay += g3.y * c3; az += g3.z * c3; aw += g3.w * c3;
    }
    for (; p < p1; ++p) {
        int s = csr_src[p];
        float cf = dinv[s] * di;
        float4 g = *(const float4*)&Hm[(size_t)s * M + j0];
        ax += g.x * cf; ay += g.y * cf; az += g.z * cf; aw += g.w * cf;
    }

    float4 outv = {ax, ay, az, aw};
    *(float4*)&Out[(size_t)i * M + j0] = outv;
}

// ---------------- BN column stats (sum, sumsq) ----------------

__global__ void k_stats(const float* __restrict__ A, int N,
                        float* __restrict__ colsum, float* __restrict__ colsq) {
    int j = threadIdx.x & 127;
    int half = threadIdx.x >> 7;  // 0 or 1
    int rend = min(N, (int)(blockIdx.x * 128 + 128));
    float s = 0.f, sq = 0.f;
    for (int r = blockIdx.x * 128 + half; r < rend; r += 2) {
        float v = A[(size_t)r * 128 + j];
        s += v; sq += v * v;
    }
    atomicAdd(&colsum[j], s);
    atomicAdd(&colsq[j], sq);
}

// ---------------- BN normalize + ReLU (+ optional skip) ----------------

__global__ void k_bnrelu(const float* __restrict__ A, const float* __restrict__ colsum,
                         const float* __restrict__ colsq, const float* __restrict__ g,
                         const float* __restrict__ be, const float* __restrict__ skip,
                         float* __restrict__ Out, int N) {
    int idx = blockIdx.x * 256 + threadIdx.x;
    int total = N * 128;
    if (idx >= total) return;
    int j = idx & 127;
    float invN = 1.0f / (float)N;
    float m = colsum[j] * invN;
    float v = colsq[j] * invN - m * m;
    float rstd = rsqrtf(v + BN_EPS);
    float y = (A[idx] - m) * rstd * g[j] + be[j];
    y = fmaxf(y, 0.0f);
    if (skip) y += skip[idx];
    Out[idx] = y;
}

// ---------------- launch ----------------

extern "C" void kernel_launch(void* const* d_in, const int* in_sizes, int n_in,
                              void* d_out, int out_size, void* d_ws, size_t ws_size,
                              hipStream_t stream) {
    const float* x   = (const float*)d_in[0];
    const int*   ei  = (const int*)d_in[1];
    const float* W1  = (const float*)d_in[2];
    const float* b1  = (const float*)d_in[3];
    const float* g1  = (const float*)d_in[4];
    const float* be1 = (const float*)d_in[5];
    const float* W2  = (const float*)d_in[6];
    const float* b2  = (const float*)d_in[7];
    const float* g2  = (const float*)d_in[8];
    const float* be2 = (const float*)d_in[9];
    const float* W3  = (const float*)d_in[10];
    const float* b3  = (const float*)d_in[11];

    int N = in_sizes[0] / 128;
    int E = in_sizes[1] / 2;
    const int* srcp = ei;
    const int* dstp = ei + E;

    char* ws = (char*)d_ws;
    size_t off = 0;
    auto alloc = [&](size_t bytes) {
        void* p = ws + off;
        off += (bytes + 255) & ~(size_t)255;
        return p;
    };

    int*   counts   = (int*)alloc((size_t)N * 4);
    int*   rowptr   = (int*)alloc(((size_t)N + 1) * 4);
    int*   cursor   = (int*)alloc((size_t)N * 4);
    int*   blockTot = (int*)alloc(512 * 4);
    int*   csr_src  = (int*)alloc((size_t)E * 4);
    float* dinv     = (float*)alloc((size_t)N * 4);
    float* stats    = (float*)alloc(256 * 4);     // colsum[128] | colsq[128]
    float* colsum = stats, *colsq = stats + 128;
    float* buf0 = (float*)alloc((size_t)N * 128 * 4);  // h
    float* buf1 = (float*)alloc((size_t)N * 128 * 4);  // agg
    float* buf2 = (float*)alloc((size_t)N * 128 * 4);  // x1 / x2
    float* outp = (float*)d_out;

    int nb1 = (N + 255) / 256;

    // CSR build + dinv
    hipMemsetAsync(counts, 0, (size_t)N * 4, stream);
    k_count<<<(E + 255) / 256, 256, 0, stream>>>(dstp, E, counts);
    k_scan1<<<nb1, 256, 0, stream>>>(counts, N, rowptr, blockTot);
    k_scan2<<<1, 512, 0, stream>>>(blockTot, nb1);
    k_scan3<<<nb1, 256, 0, stream>>>(counts, N, E, rowptr, blockTot, cursor, dinv);
    k_fill<<<(E + 255) / 256, 256, 0, stream>>>(srcp, dstp, E, rowptr, cursor, csr_src);

    // layer 1
    k_gemm<128, 32><<<(N + 31) / 32, 256, 0, stream>>>(x, W1, buf0, N);
    k_agg<128><<<(N + 7) / 8, 256, 0, stream>>>(buf0, rowptr, csr_src, dinv, b1, buf1, N);
    hipMemsetAsync(stats, 0, 256 * 4, stream);
    k_stats<<<(N + 127) / 128, 256, 0, stream>>>(buf1, N, colsum, colsq);
    k_bnrelu<<<((size_t)N * 128 + 255) / 256, 256, 0, stream>>>(buf1, colsum, colsq, g1, be1,
                                                                nullptr, buf2, N);
    // layer 2
    k_gemm<128, 32><<<(N + 31) / 32, 256, 0, stream>>>(buf2, W2, buf0, N);
    k_agg<128><<<(N + 7) / 8, 256, 0, stream>>>(buf0, rowptr, csr_src, dinv, b2, buf1, N);
    hipMemsetAsync(stats, 0, 256 * 4, stream);
    k_stats<<<(N + 127) / 128, 256, 0, stream>>>(buf1, N, colsum, colsq);
    k_bnrelu<<<((size_t)N * 128 + 255) / 256, 256, 0, stream>>>(buf1, colsum, colsq, g2, be2,
                                                                buf2, buf2, N);
    // layer 3
    k_gemm<64, 64><<<(N + 63) / 64, 256, 0, stream>>>(buf2, W3, buf0, N);
    k_agg<64><<<(N + 15) / 16, 256, 0, stream>>>(buf0, rowptr, csr_src, dinv, b3, outp, N);
}

// Round 3
// 818.294 us; speedup vs baseline: 1.5357x; 1.0541x over previous
//
#include <hip/hip_runtime.h>

#define BN_EPS 1e-5f

// ---------------- CSR build ----------------

__global__ void k_count(const int* __restrict__ dst, int E, int* __restrict__ counts) {
    int e = blockIdx.x * blockDim.x + threadIdx.x;
    if (e < E) atomicAdd(&counts[dst[e]], 1);
}

__global__ void k_scan1(const int* __restrict__ counts, int N,
                        int* __restrict__ rowptr, int* __restrict__ blockTot) {
    __shared__ int sh[256];
    int t = threadIdx.x;
    int i = blockIdx.x * 256 + t;
    int v = (i < N) ? counts[i] : 0;
    sh[t] = v;
    __syncthreads();
    for (int off = 1; off < 256; off <<= 1) {
        int x = (t >= off) ? sh[t - off] : 0;
        __syncthreads();
        sh[t] += x;
        __syncthreads();
    }
    int incl = sh[t];
    if (i < N) rowptr[i] = incl - v;              // local exclusive
    if (t == 255) blockTot[blockIdx.x] = incl;    // block total
}

__global__ void k_scan2(int* __restrict__ blockTot, int nb) {
    __shared__ int sh[512];
    int t = threadIdx.x;
    int v = (t < nb) ? blockTot[t] : 0;
    sh[t] = v;
    __syncthreads();
    for (int off = 1; off < 512; off <<= 1) {
        int x = (t >= off) ? sh[t - off] : 0;
        __syncthreads();
        sh[t] += x;
        __syncthreads();
    }
    if (t < nb) blockTot[t] = sh[t] - v;          // exclusive block offsets
}

__global__ void k_scan3(const int* __restrict__ counts, int N, int E,
                        int* __restrict__ rowptr, const int* __restrict__ blockTot,
                        int* __restrict__ cursor, float* __restrict__ dinv) {
    int i = blockIdx.x * 256 + threadIdx.x;
    if (i < N) {
        rowptr[i] += blockTot[blockIdx.x];
        cursor[i] = 0;
        dinv[i] = rsqrtf((float)counts[i] + 1.0f);  // deg = in-degree + self-loop
    }
    if (i == 0) rowptr[N] = E;
}

// meta[pos] = {src_index (bitcast), dinv[src]} — one 8B load per edge in k_agg.
__global__ void k_fill(const int* __restrict__ src, const int* __restrict__ dst, int E,
                       const int* __restrict__ rowptr, int* __restrict__ cursor,
                       const float* __restrict__ dinv, float2* __restrict__ meta) {
    int e = blockIdx.x * blockDim.x + threadIdx.x;
    if (e < E) {
        int d = dst[e];
        int s = src[e];
        int pos = rowptr[d] + atomicAdd(&cursor[d], 1);
        meta[pos] = make_float2(__int_as_float(s), dinv[s]);
    }
}

// ---------------- GEMM: Hout[N,M] = X[N,128] @ W[128,M] ----------------

template<int M, int ROWS>
__global__ __launch_bounds__(256) void k_gemm(const float* __restrict__ X,
                                              const float* __restrict__ W,
                                              float* __restrict__ Hout, int N) {
    __shared__ float Ws[128 * M];
    __shared__ float XsT[128 * ROWS];
    constexpr int CG = M / 4;          // column groups of 4
    constexpr int RG = 256 / CG;       // row groups
    static_assert(ROWS / RG == 4, "4 rows per thread");

    int t = threadIdx.x;
    int r0b = blockIdx.x * ROWS;

    for (int i4 = t; i4 < 32 * M; i4 += 256)
        ((float4*)Ws)[i4] = ((const float4*)W)[i4];

    for (int idx = t; idx < ROWS * 32; idx += 256) {
        int r = idx >> 5, kq = idx & 31;
        float4 v = {0.f, 0.f, 0.f, 0.f};
        int row = r0b + r;
        if (row < N) v = ((const float4*)(X + (size_t)row * 128))[kq];
        XsT[(4 * kq + 0) * ROWS + r] = v.x;
        XsT[(4 * kq + 1) * ROWS + r] = v.y;
        XsT[(4 * kq + 2) * ROWS + r] = v.z;
        XsT[(4 * kq + 3) * ROWS + r] = v.w;
    }
    __syncthreads();

    int c = t % CG, rg = t / CG;
    int j0 = c * 4, r0 = rg * 4;
    float4 a0 = {0,0,0,0}, a1 = {0,0,0,0}, a2 = {0,0,0,0}, a3 = {0,0,0,0};

#pragma unroll 8
    for (int k = 0; k < 128; ++k) {
        float4 wv = *(const float4*)&Ws[k * M + j0];
        float4 xv = *(const float4*)&XsT[k * ROWS + r0];
        a0.x += xv.x * wv.x; a0.y += xv.x * wv.y; a0.z += xv.x * wv.z; a0.w += xv.x * wv.w;
        a1.x += xv.y * wv.x; a1.y += xv.y * wv.y; a1.z += xv.y * wv.z; a1.w += xv.y * wv.w;
        a2.x += xv.z * wv.x; a2.y += xv.z * wv.y; a2.z += xv.z * wv.z; a2.w += xv.z * wv.w;
        a3.x += xv.w * wv.x; a3.y += xv.w * wv.y; a3.z += xv.w * wv.z; a3.w += xv.w * wv.w;
    }

    float4 accs[4] = {a0, a1, a2, a3};
#pragma unroll
    for (int i = 0; i < 4; ++i) {
        int row = r0b + r0 + i;
        if (row < N) *(float4*)&Hout[(size_t)row * M + j0] = accs[i];
    }
}

// ---------------- Aggregation ----------------
// raw = sum_e c_e * h[src_e]   (c_e = dinv[src_e], prefetched in meta)
// out = (raw + h[i]*di) * di + bias
// Software-pipelined: next iteration's meta loads are issued before the
// accumulate so the gather waitcnt leaves them in flight (1 round trip/iter).

template<int M>
__global__ __launch_bounds__(256) void k_agg(const float* __restrict__ Hm,
                      const int* __restrict__ rowptr,
                      const float2* __restrict__ meta, const float* __restrict__ dinv,
                      const float* __restrict__ bias, float* __restrict__ Out, int N) {
    constexpr int TPN = M / 4;           // threads per node
    constexpr int NPB = 256 / TPN;       // nodes per block
    int li = threadIdx.x / TPN;
    int lane = threadIdx.x % TPN;
    int i = blockIdx.x * NPB + li;
    if (i >= N) return;
    int j0 = lane * 4;

    int p = rowptr[i], p1 = rowptr[i + 1];
    float ax = 0.f, ay = 0.f, az = 0.f, aw = 0.f;

    float2 m0, m1, m2, m3;
    bool have = (p + 3 < p1);
    if (have) { m0 = meta[p]; m1 = meta[p + 1]; m2 = meta[p + 2]; m3 = meta[p + 3]; }
    while (have) {
        int   s0 = __float_as_int(m0.x); float c0 = m0.y;
        int   s1 = __float_as_int(m1.x); float c1 = m1.y;
        int   s2 = __float_as_int(m2.x); float c2 = m2.y;
        int   s3 = __float_as_int(m3.x); float c3 = m3.y;
        float4 g0 = *(const float4*)&Hm[(size_t)s0 * M + j0];
        float4 g1 = *(const float4*)&Hm[(size_t)s1 * M + j0];
        float4 g2 = *(const float4*)&Hm[(size_t)s2 * M + j0];
        float4 g3 = *(const float4*)&Hm[(size_t)s3 * M + j0];
        p += 4;
        have = (p + 3 < p1);
        if (have) { m0 = meta[p]; m1 = meta[p + 1]; m2 = meta[p + 2]; m3 = meta[p + 3]; }
        ax += g0.x * c0; ay += g0.y * c0; az += g0.z * c0; aw += g0.w * c0;
        ax += g1.x * c1; ay += g1.y * c1; az += g1.z * c1; aw += g1.w * c1;
        ax += g2.x * c2; ay += g2.y * c2; az += g2.z * c2; aw += g2.w * c2;
        ax += g3.x * c3; ay += g3.y * c3; az += g3.z * c3; aw += g3.w * c3;
    }
    for (; p < p1; ++p) {
        float2 mm = meta[p];
        int s = __float_as_int(mm.x); float cf = mm.y;
        float4 g = *(const float4*)&Hm[(size_t)s * M + j0];
        ax += g.x * cf; ay += g.y * cf; az += g.z * cf; aw += g.w * cf;
    }

    float di = dinv[i];
    float4 hv = *(const float4*)&Hm[(size_t)i * M + j0];
    float4 bv = *(const float4*)&bias[j0];
    float4 outv;
    outv.x = (ax + hv.x * di) * di + bv.x;
    outv.y = (ay + hv.y * di) * di + bv.y;
    outv.z = (az + hv.z * di) * di + bv.z;
    outv.w = (aw + hv.w * di) * di + bv.w;
    *(float4*)&Out[(size_t)i * M + j0] = outv;
}

// ---------------- BN column stats (sum, sumsq) ----------------

__global__ void k_stats(const float* __restrict__ A, int N,
                        float* __restrict__ colsum, float* __restrict__ colsq) {
    int j = threadIdx.x & 127;
    int half = threadIdx.x >> 7;  // 0 or 1
    int rend = min(N, (int)(blockIdx.x * 128 + 128));
    float s = 0.f, sq = 0.f;
    for (int r = blockIdx.x * 128 + half; r < rend; r += 2) {
        float v = A[(size_t)r * 128 + j];
        s += v; sq += v * v;
    }
    atomicAdd(&colsum[j], s);
    atomicAdd(&colsq[j], sq);
}

// ---------------- BN normalize + ReLU (+ optional skip) ----------------

__global__ void k_bnrelu(const float* __restrict__ A, const float* __restrict__ colsum,
                         const float* __restrict__ colsq, const float* __restrict__ g,
                         const float* __restrict__ be, const float* __restrict__ skip,
                         float* __restrict__ Out, int N) {
    int idx = blockIdx.x * 256 + threadIdx.x;
    int total = N * 128;
    if (idx >= total) return;
    int j = idx & 127;
    float invN = 1.0f / (float)N;
    float m = colsum[j] * invN;
    float v = colsq[j] * invN - m * m;
    float rstd = rsqrtf(v + BN_EPS);
    float y = (A[idx] - m) * rstd * g[j] + be[j];
    y = fmaxf(y, 0.0f);
    if (skip) y += skip[idx];
    Out[idx] = y;
}

// ---------------- launch ----------------

extern "C" void kernel_launch(void* const* d_in, const int* in_sizes, int n_in,
                              void* d_out, int out_size, void* d_ws, size_t ws_size,
                              hipStream_t stream) {
    const float* x   = (const float*)d_in[0];
    const int*   ei  = (const int*)d_in[1];
    const float* W1  = (const float*)d_in[2];
    const float* b1  = (const float*)d_in[3];
    const float* g1  = (const float*)d_in[4];
    const float* be1 = (const float*)d_in[5];
    const float* W2  = (const float*)d_in[6];
    const float* b2  = (const float*)d_in[7];
    const float* g2  = (const float*)d_in[8];
    const float* be2 = (const float*)d_in[9];
    const float* W3  = (const float*)d_in[10];
    const float* b3  = (const float*)d_in[11];

    int N = in_sizes[0] / 128;
    int E = in_sizes[1] / 2;
    const int* srcp = ei;
    const int* dstp = ei + E;

    char* ws = (char*)d_ws;
    size_t off = 0;
    auto alloc = [&](size_t bytes) {
        void* p = ws + off;
        off += (bytes + 255) & ~(size_t)255;
        return p;
    };

    int*   counts   = (int*)alloc((size_t)N * 4);
    int*   rowptr   = (int*)alloc(((size_t)N + 1) * 4);
    int*   cursor   = (int*)alloc((size_t)N * 4);
    int*   blockTot = (int*)alloc(512 * 4);
    float2* meta    = (float2*)alloc((size_t)E * 8);
    float* dinv     = (float*)alloc((size_t)N * 4);
    float* stats    = (float*)alloc(256 * 4);     // colsum[128] | colsq[128]
    float* colsum = stats, *colsq = stats + 128;
    float* buf0 = (float*)alloc((size_t)N * 128 * 4);  // h
    float* buf1 = (float*)alloc((size_t)N * 128 * 4);  // agg
    float* buf2 = (float*)alloc((size_t)N * 128 * 4);  // x1 / x2
    float* outp = (float*)d_out;

    int nb1 = (N + 255) / 256;

    // CSR build + dinv
    hipMemsetAsync(counts, 0, (size_t)N * 4, stream);
    k_count<<<(E + 255) / 256, 256, 0, stream>>>(dstp, E, counts);
    k_scan1<<<nb1, 256, 0, stream>>>(counts, N, rowptr, blockTot);
    k_scan2<<<1, 512, 0, stream>>>(blockTot, nb1);
    k_scan3<<<nb1, 256, 0, stream>>>(counts, N, E, rowptr, blockTot, cursor, dinv);
    k_fill<<<(E + 255) / 256, 256, 0, stream>>>(srcp, dstp, E, rowptr, cursor, dinv, meta);

    // layer 1
    k_gemm<128, 32><<<(N + 31) / 32, 256, 0, stream>>>(x, W1, buf0, N);
    k_agg<128><<<(N + 7) / 8, 256, 0, stream>>>(buf0, rowptr, meta, dinv, b1, buf1, N);
    hipMemsetAsync(stats, 0, 256 * 4, stream);
    k_stats<<<(N + 127) / 128, 256, 0, stream>>>(buf1, N, colsum, colsq);
    k_bnrelu<<<((size_t)N * 128 + 255) / 256, 256, 0, stream>>>(buf1, colsum, colsq, g1, be1,
                                                                nullptr, buf2, N);
    // layer 2
    k_gemm<128, 32><<<(N + 31) / 32, 256, 0, stream>>>(buf2, W2, buf0, N);
    k_agg<128><<<(N + 7) / 8, 256, 0, stream>>>(buf0, rowptr, meta, dinv, b2, buf1, N);
    hipMemsetAsync(stats, 0, 256 * 4, stream);
    k_stats<<<(N + 127) / 128, 256, 0, stream>>>(buf1, N, colsum, colsq);
    k_bnrelu<<<((size_t)N * 128 + 255) / 256, 256, 0, stream>>>(buf1, colsum, colsq, g2, be2,
                                                                buf2, buf2, N);
    // layer 3
    k_gemm<64, 64><<<(N + 63) / 64, 256, 0, stream>>>(buf2, W3, buf0, N);
    k_agg<64><<<(N + 15) / 16, 256, 0, stream>>>(buf0, rowptr, meta, dinv, b3, outp, N);
}

// Round 4
// 683.417 us; speedup vs baseline: 1.8388x; 1.1974x over previous
//
#include <hip/hip_runtime.h>

#define BN_EPS 1e-5f

typedef unsigned short ushort_t;

// round-to-nearest-even fp32 -> bf16 (finite inputs)
__device__ __forceinline__ ushort_t bf16rne(float f) {
    unsigned int u = __float_as_uint(f);
    unsigned int r = (u + 0x7FFFu + ((u >> 16) & 1u)) >> 16;
    return (ushort_t)r;
}
// u32 holding two packed bf16 -> two floats
__device__ __forceinline__ void cvt2(unsigned int u, float& lo, float& hi) {
    lo = __uint_as_float(u << 16);
    hi = __uint_as_float(u & 0xFFFF0000u);
}

// ---------------- CSR build ----------------

__global__ void k_count(const int* __restrict__ dst, int E, int* __restrict__ counts) {
    int e = blockIdx.x * blockDim.x + threadIdx.x;
    if (e < E) atomicAdd(&counts[dst[e]], 1);
}

__global__ void k_scan1(const int* __restrict__ counts, int N,
                        int* __restrict__ rowptr, int* __restrict__ blockTot) {
    __shared__ int sh[256];
    int t = threadIdx.x;
    int i = blockIdx.x * 256 + t;
    int v = (i < N) ? counts[i] : 0;
    sh[t] = v;
    __syncthreads();
    for (int off = 1; off < 256; off <<= 1) {
        int x = (t >= off) ? sh[t - off] : 0;
        __syncthreads();
        sh[t] += x;
        __syncthreads();
    }
    int incl = sh[t];
    if (i < N) rowptr[i] = incl - v;
    if (t == 255) blockTot[blockIdx.x] = incl;
}

__global__ void k_scan2(int* __restrict__ blockTot, int nb) {
    __shared__ int sh[512];
    int t = threadIdx.x;
    int v = (t < nb) ? blockTot[t] : 0;
    sh[t] = v;
    __syncthreads();
    for (int off = 1; off < 512; off <<= 1) {
        int x = (t >= off) ? sh[t - off] : 0;
        __syncthreads();
        sh[t] += x;
        __syncthreads();
    }
    if (t < nb) blockTot[t] = sh[t] - v;
}

__global__ void k_scan3(const int* __restrict__ counts, int N, int E,
                        int* __restrict__ rowptr, const int* __restrict__ blockTot,
                        int* __restrict__ cursor, float* __restrict__ dinv) {
    int i = blockIdx.x * 256 + threadIdx.x;
    if (i < N) {
        rowptr[i] += blockTot[blockIdx.x];
        cursor[i] = 0;
        dinv[i] = rsqrtf((float)counts[i] + 1.0f);
    }
    if (i == 0) rowptr[N] = E;
}

// meta[pos] = {src_index (bitcast), dinv[src]}
__global__ void k_fill(const int* __restrict__ src, const int* __restrict__ dst, int E,
                       const int* __restrict__ rowptr, int* __restrict__ cursor,
                       const float* __restrict__ dinv, float2* __restrict__ meta) {
    int e = blockIdx.x * blockDim.x + threadIdx.x;
    if (e < E) {
        int d = dst[e];
        int s = src[e];
        int pos = rowptr[d] + atomicAdd(&cursor[d], 1);
        meta[pos] = make_float2(__int_as_float(s), dinv[s]);
    }
}

// ---------------- GEMM: Hout[N,M](bf16) = X[N,128](fp32) @ W[128,M] ----------------

template<int M, int ROWS>
__global__ __launch_bounds__(256) void k_gemm(const float* __restrict__ X,
                                              const float* __restrict__ W,
                                              ushort_t* __restrict__ Hout, int N) {
    __shared__ float Ws[128 * M];
    __shared__ float XsT[128 * ROWS];
    constexpr int CG = M / 4;
    constexpr int RG = 256 / CG;
    static_assert(ROWS / RG == 4, "4 rows per thread");

    int t = threadIdx.x;
    int r0b = blockIdx.x * ROWS;

    for (int i4 = t; i4 < 32 * M; i4 += 256)
        ((float4*)Ws)[i4] = ((const float4*)W)[i4];

    for (int idx = t; idx < ROWS * 32; idx += 256) {
        int r = idx >> 5, kq = idx & 31;
        float4 v = {0.f, 0.f, 0.f, 0.f};
        int row = r0b + r;
        if (row < N) v = ((const float4*)(X + (size_t)row * 128))[kq];
        XsT[(4 * kq + 0) * ROWS + r] = v.x;
        XsT[(4 * kq + 1) * ROWS + r] = v.y;
        XsT[(4 * kq + 2) * ROWS + r] = v.z;
        XsT[(4 * kq + 3) * ROWS + r] = v.w;
    }
    __syncthreads();

    int c = t % CG, rg = t / CG;
    int j0 = c * 4, r0 = rg * 4;
    float4 a0 = {0,0,0,0}, a1 = {0,0,0,0}, a2 = {0,0,0,0}, a3 = {0,0,0,0};

#pragma unroll 8
    for (int k = 0; k < 128; ++k) {
        float4 wv = *(const float4*)&Ws[k * M + j0];
        float4 xv = *(const float4*)&XsT[k * ROWS + r0];
        a0.x += xv.x * wv.x; a0.y += xv.x * wv.y; a0.z += xv.x * wv.z; a0.w += xv.x * wv.w;
        a1.x += xv.y * wv.x; a1.y += xv.y * wv.y; a1.z += xv.y * wv.z; a1.w += xv.y * wv.w;
        a2.x += xv.z * wv.x; a2.y += xv.z * wv.y; a2.z += xv.z * wv.z; a2.w += xv.z * wv.w;
        a3.x += xv.w * wv.x; a3.y += xv.w * wv.y; a3.z += xv.w * wv.z; a3.w += xv.w * wv.w;
    }

    float4 accs[4] = {a0, a1, a2, a3};
#pragma unroll
    for (int i = 0; i < 4; ++i) {
        int row = r0b + r0 + i;
        if (row < N) {
            ushort4 o;
            o.x = bf16rne(accs[i].x); o.y = bf16rne(accs[i].y);
            o.z = bf16rne(accs[i].z); o.w = bf16rne(accs[i].w);
            *(ushort4*)&Hout[(size_t)row * M + j0] = o;
        }
    }
}

// ---------------- Aggregation (bf16 gather, fp32 accumulate) ----------------
// out = (sum_e c_e*h[src_e] + h[i]*di) * di + bias
// Each lane owns 8 columns (one uint4 = 8 bf16 per gather).

template<int M>
__global__ __launch_bounds__(256) void k_agg(const ushort_t* __restrict__ Hm,
                      const int* __restrict__ rowptr,
                      const float2* __restrict__ meta, const float* __restrict__ dinv,
                      const float* __restrict__ bias, float* __restrict__ Out, int N) {
    constexpr int TPN = M / 8;           // threads per node
    constexpr int NPB = 256 / TPN;       // nodes per block
    int li = threadIdx.x / TPN;
    int lane = threadIdx.x % TPN;
    int i = blockIdx.x * NPB + li;
    if (i >= N) return;
    int j0 = lane * 8;

    int p = rowptr[i], p1 = rowptr[i + 1];
    float a0 = 0.f, a1 = 0.f, a2 = 0.f, a3 = 0.f, a4 = 0.f, a5 = 0.f, a6 = 0.f, a7 = 0.f;

    float2 m0, m1, m2, m3;
    bool have = (p + 3 < p1);
    if (have) { m0 = meta[p]; m1 = meta[p + 1]; m2 = meta[p + 2]; m3 = meta[p + 3]; }
    while (have) {
        int   s0 = __float_as_int(m0.x); float c0 = m0.y;
        int   s1 = __float_as_int(m1.x); float c1 = m1.y;
        int   s2 = __float_as_int(m2.x); float c2 = m2.y;
        int   s3 = __float_as_int(m3.x); float c3 = m3.y;
        uint4 g0 = *(const uint4*)&Hm[(size_t)s0 * M + j0];
        uint4 g1 = *(const uint4*)&Hm[(size_t)s1 * M + j0];
        uint4 g2 = *(const uint4*)&Hm[(size_t)s2 * M + j0];
        uint4 g3 = *(const uint4*)&Hm[(size_t)s3 * M + j0];
        p += 4;
        have = (p + 3 < p1);
        if (have) { m0 = meta[p]; m1 = meta[p + 1]; m2 = meta[p + 2]; m3 = meta[p + 3]; }
        float lo, hi;
        cvt2(g0.x, lo, hi); a0 += lo * c0; a1 += hi * c0;
        cvt2(g0.y, lo, hi); a2 += lo * c0; a3 += hi * c0;
        cvt2(g0.z, lo, hi); a4 += lo * c0; a5 += hi * c0;
        cvt2(g0.w, lo, hi); a6 += lo * c0; a7 += hi * c0;
        cvt2(g1.x, lo, hi); a0 += lo * c1; a1 += hi * c1;
        cvt2(g1.y, lo, hi); a2 += lo * c1; a3 += hi * c1;
        cvt2(g1.z, lo, hi); a4 += lo * c1; a5 += hi * c1;
        cvt2(g1.w, lo, hi); a6 += lo * c1; a7 += hi * c1;
        cvt2(g2.x, lo, hi); a0 += lo * c2; a1 += hi * c2;
        cvt2(g2.y, lo, hi); a2 += lo * c2; a3 += hi * c2;
        cvt2(g2.z, lo, hi); a4 += lo * c2; a5 += hi * c2;
        cvt2(g2.w, lo, hi); a6 += lo * c2; a7 += hi * c2;
        cvt2(g3.x, lo, hi); a0 += lo * c3; a1 += hi * c3;
        cvt2(g3.y, lo, hi); a2 += lo * c3; a3 += hi * c3;
        cvt2(g3.z, lo, hi); a4 += lo * c3; a5 += hi * c3;
        cvt2(g3.w, lo, hi); a6 += lo * c3; a7 += hi * c3;
    }
    for (; p < p1; ++p) {
        float2 mm = meta[p];
        int s = __float_as_int(mm.x); float cf = mm.y;
        uint4 g = *(const uint4*)&Hm[(size_t)s * M + j0];
        float lo, hi;
        cvt2(g.x, lo, hi); a0 += lo * cf; a1 += hi * cf;
        cvt2(g.y, lo, hi); a2 += lo * cf; a3 += hi * cf;
        cvt2(g.z, lo, hi); a4 += lo * cf; a5 += hi * cf;
        cvt2(g.w, lo, hi); a6 += lo * cf; a7 += hi * cf;
    }

    float di = dinv[i];
    uint4 hs = *(const uint4*)&Hm[(size_t)i * M + j0];
    float lo, hi;
    cvt2(hs.x, lo, hi); a0 += lo * di; a1 += hi * di;
    cvt2(hs.y, lo, hi); a2 += lo * di; a3 += hi * di;
    cvt2(hs.z, lo, hi); a4 += lo * di; a5 += hi * di;
    cvt2(hs.w, lo, hi); a6 += lo * di; a7 += hi * di;

    float4 bv0 = *(const float4*)&bias[j0];
    float4 bv1 = *(const float4*)&bias[j0 + 4];
    float4 o0, o1;
    o0.x = a0 * di + bv0.x; o0.y = a1 * di + bv0.y;
    o0.z = a2 * di + bv0.z; o0.w = a3 * di + bv0.w;
    o1.x = a4 * di + bv1.x; o1.y = a5 * di + bv1.y;
    o1.z = a6 * di + bv1.z; o1.w = a7 * di + bv1.w;
    *(float4*)&Out[(size_t)i * M + j0] = o0;
    *(float4*)&Out[(size_t)i * M + j0 + 4] = o1;
}

// ---------------- BN column stats (sum, sumsq) ----------------

__global__ void k_stats(const float* __restrict__ A, int N,
                        float* __restrict__ colsum, float* __restrict__ colsq) {
    int j = threadIdx.x & 127;
    int half = threadIdx.x >> 7;
    int rend = min(N, (int)(blockIdx.x * 128 + 128));
    float s = 0.f, sq = 0.f;
    for (int r = blockIdx.x * 128 + half; r < rend; r += 2) {
        float v = A[(size_t)r * 128 + j];
        s += v; sq += v * v;
    }
    atomicAdd(&colsum[j], s);
    atomicAdd(&colsq[j], sq);
}

// ---------------- BN normalize + ReLU (+ optional skip) ----------------

__global__ void k_bnrelu(const float* __restrict__ A, const float* __restrict__ colsum,
                         const float* __restrict__ colsq, const float* __restrict__ g,
                         const float* __restrict__ be, const float* __restrict__ skip,
                         float* __restrict__ Out, int N) {
    int idx = blockIdx.x * 256 + threadIdx.x;
    int total = N * 128;
    if (idx >= total) return;
    int j = idx & 127;
    float invN = 1.0f / (float)N;
    float m = colsum[j] * invN;
    float v = colsq[j] * invN - m * m;
    float rstd = rsqrtf(v + BN_EPS);
    float y = (A[idx] - m) * rstd * g[j] + be[j];
    y = fmaxf(y, 0.0f);
    if (skip) y += skip[idx];
    Out[idx] = y;
}

// ---------------- launch ----------------

extern "C" void kernel_launch(void* const* d_in, const int* in_sizes, int n_in,
                              void* d_out, int out_size, void* d_ws, size_t ws_size,
                              hipStream_t stream) {
    const float* x   = (const float*)d_in[0];
    const int*   ei  = (const int*)d_in[1];
    const float* W1  = (const float*)d_in[2];
    const float* b1  = (const float*)d_in[3];
    const float* g1  = (const float*)d_in[4];
    const float* be1 = (const float*)d_in[5];
    const float* W2  = (const float*)d_in[6];
    const float* b2  = (const float*)d_in[7];
    const float* g2  = (const float*)d_in[8];
    const float* be2 = (const float*)d_in[9];
    const float* W3  = (const float*)d_in[10];
    const float* b3  = (const float*)d_in[11];

    int N = in_sizes[0] / 128;
    int E = in_sizes[1] / 2;
    const int* srcp = ei;
    const int* dstp = ei + E;

    char* ws = (char*)d_ws;
    size_t off = 0;
    auto alloc = [&](size_t bytes) {
        void* p = ws + off;
        off += (bytes + 255) & ~(size_t)255;
        return p;
    };

    int*   counts   = (int*)alloc((size_t)N * 4);
    int*   rowptr   = (int*)alloc(((size_t)N + 1) * 4);
    int*   cursor   = (int*)alloc((size_t)N * 4);
    int*   blockTot = (int*)alloc(512 * 4);
    float2* meta    = (float2*)alloc((size_t)E * 8);
    float* dinv     = (float*)alloc((size_t)N * 4);
    float* stats    = (float*)alloc(256 * 4);
    float* colsum = stats, *colsq = stats + 128;
    ushort_t* hbuf  = (ushort_t*)alloc((size_t)N * 128 * 2);  // bf16 h-table
    float* buf1 = (float*)alloc((size_t)N * 128 * 4);         // agg out
    float* buf2 = (float*)alloc((size_t)N * 128 * 4);         // x1 / x2
    float* outp = (float*)d_out;

    int nb1 = (N + 255) / 256;

    // CSR build + dinv
    hipMemsetAsync(counts, 0, (size_t)N * 4, stream);
    k_count<<<(E + 255) / 256, 256, 0, stream>>>(dstp, E, counts);
    k_scan1<<<nb1, 256, 0, stream>>>(counts, N, rowptr, blockTot);
    k_scan2<<<1, 512, 0, stream>>>(blockTot, nb1);
    k_scan3<<<nb1, 256, 0, stream>>>(counts, N, E, rowptr, blockTot, cursor, dinv);
    k_fill<<<(E + 255) / 256, 256, 0, stream>>>(srcp, dstp, E, rowptr, cursor, dinv, meta);

    // layer 1
    k_gemm<128, 32><<<(N + 31) / 32, 256, 0, stream>>>(x, W1, hbuf, N);
    k_agg<128><<<(N + 15) / 16, 256, 0, stream>>>(hbuf, rowptr, meta, dinv, b1, buf1, N);
    hipMemsetAsync(stats, 0, 256 * 4, stream);
    k_stats<<<(N + 127) / 128, 256, 0, stream>>>(buf1, N, colsum, colsq);
    k_bnrelu<<<((size_t)N * 128 + 255) / 256, 256, 0, stream>>>(buf1, colsum, colsq, g1, be1,
                                                                nullptr, buf2, N);
    // layer 2
    k_gemm<128, 32><<<(N + 31) / 32, 256, 0, stream>>>(buf2, W2, hbuf, N);
    k_agg<128><<<(N + 15) / 16, 256, 0, stream>>>(hbuf, rowptr, meta, dinv, b2, buf1, N);
    hipMemsetAsync(stats, 0, 256 * 4, stream);
    k_stats<<<(N + 127) / 128, 256, 0, stream>>>(buf1, N, colsum, colsq);
    k_bnrelu<<<((size_t)N * 128 + 255) / 256, 256, 0, stream>>>(buf1, colsum, colsq, g2, be2,
                                                                buf2, buf2, N);
    // layer 3
    k_gemm<64, 64><<<(N + 63) / 64, 256, 0, stream>>>(buf2, W3, hbuf, N);
    k_agg<64><<<(N + 31) / 32, 256, 0, stream>>>(hbuf, rowptr, meta, dinv, b3, outp, N);
}

// Round 5
// 625.389 us; speedup vs baseline: 2.0094x; 1.0928x over previous
//
#include <hip/hip_runtime.h>

#define BN_EPS 1e-5f

typedef unsigned short ushort_t;

// round-to-nearest-even fp32 -> bf16 (finite inputs)
__device__ __forceinline__ ushort_t bf16rne(float f) {
    unsigned int u = __float_as_uint(f);
    unsigned int r = (u + 0x7FFFu + ((u >> 16) & 1u)) >> 16;
    return (ushort_t)r;
}
__device__ __forceinline__ float bf16tof(ushort_t u) {
    return __uint_as_float(((unsigned int)u) << 16);
}
// u32 holding two packed bf16 -> two floats
__device__ __forceinline__ void cvt2(unsigned int u, float& lo, float& hi) {
    lo = __uint_as_float(u << 16);
    hi = __uint_as_float(u & 0xFFFF0000u);
}

// ---------------- CSR build ----------------

__global__ void k_count(const int* __restrict__ dst, int E, int* __restrict__ counts) {
    int e = blockIdx.x * blockDim.x + threadIdx.x;
    if (e < E) atomicAdd(&counts[dst[e]], 1);
}

__global__ void k_scan1(const int* __restrict__ counts, int N,
                        int* __restrict__ rowptr, int* __restrict__ blockTot) {
    __shared__ int sh[256];
    int t = threadIdx.x;
    int i = blockIdx.x * 256 + t;
    int v = (i < N) ? counts[i] : 0;
    sh[t] = v;
    __syncthreads();
    for (int off = 1; off < 256; off <<= 1) {
        int x = (t >= off) ? sh[t - off] : 0;
        __syncthreads();
        sh[t] += x;
        __syncthreads();
    }
    int incl = sh[t];
    if (i < N) rowptr[i] = incl - v;
    if (t == 255) blockTot[blockIdx.x] = incl;
}

__global__ void k_scan2(int* __restrict__ blockTot, int nb) {
    __shared__ int sh[512];
    int t = threadIdx.x;
    int v = (t < nb) ? blockTot[t] : 0;
    sh[t] = v;
    __syncthreads();
    for (int off = 1; off < 512; off <<= 1) {
        int x = (t >= off) ? sh[t - off] : 0;
        __syncthreads();
        sh[t] += x;
        __syncthreads();
    }
    if (t < nb) blockTot[t] = sh[t] - v;
}

__global__ void k_scan3(const int* __restrict__ counts, int N, int E,
                        int* __restrict__ rowptr, const int* __restrict__ blockTot,
                        int* __restrict__ cursor, float* __restrict__ dinv) {
    int i = blockIdx.x * 256 + threadIdx.x;
    if (i < N) {
        int rp = rowptr[i] + blockTot[blockIdx.x];
        rowptr[i] = rp;
        cursor[i] = rp;                              // cursor pre-seeded = rowptr
        dinv[i] = rsqrtf((float)counts[i] + 1.0f);   // deg = in-degree + self-loop
    }
    if (i == 0) rowptr[N] = E;
}

// 4B scatter only: csr_src[pos] = src
__global__ void k_fill(const int* __restrict__ src, const int* __restrict__ dst, int E,
                       int* __restrict__ cursor, int* __restrict__ csr_src) {
    int e = blockIdx.x * blockDim.x + threadIdx.x;
    if (e < E) {
        int pos = atomicAdd(&cursor[dst[e]], 1);
        csr_src[pos] = src[e];
    }
}

// ---------------- BN params: scale/shift from spread stats ----------------
// spread layout: [0][32][128] = colsum partials, [1][32][128] = colsq partials

__global__ void k_bnparam(const float* __restrict__ sp, const float* __restrict__ g,
                          const float* __restrict__ be, float* __restrict__ scale,
                          float* __restrict__ shift, float invN) {
    int j = threadIdx.x;  // 128 threads
    float s = 0.f, q = 0.f;
#pragma unroll
    for (int w = 0; w < 32; ++w) {
        s += sp[w * 128 + j];
        q += sp[32 * 128 + w * 128 + j];
    }
    float m = s * invN;
    float var = q * invN - m * m;
    float r = rsqrtf(var + BN_EPS);
    float sc = g[j] * r;
    scale[j] = sc;
    shift[j] = be[j] - m * sc;
}

// ---------------- GEMM: Hout[N,M](bf16) = f(X)[N,128] @ W[128,M] ----------------
// MODE 0: f = identity
// MODE 1: f = relu(X*scale+shift), also writes f(X) to x1buf (bf16)
// MODE 2: f = relu(X*scale+shift) + bf16(x1buf)

template<int M, int ROWS, int MODE>
__global__ __launch_bounds__(256) void k_gemm(const float* __restrict__ X,
                                              const float* __restrict__ W,
                                              ushort_t* __restrict__ Hout, int N,
                                              const float* __restrict__ scale,
                                              const float* __restrict__ shift,
                                              ushort_t* __restrict__ x1buf) {
    __shared__ float Ws[128 * M];
    __shared__ float XsT[128 * ROWS];
    constexpr int CG = M / 4;
    constexpr int RG = 256 / CG;
    static_assert(ROWS / RG == 4, "4 rows per thread");

    int t = threadIdx.x;
    int r0b = blockIdx.x * ROWS;

    for (int i4 = t; i4 < 32 * M; i4 += 256)
        ((float4*)Ws)[i4] = ((const float4*)W)[i4];

    for (int idx = t; idx < ROWS * 32; idx += 256) {
        int r = idx >> 5, kq = idx & 31;
        float4 v = {0.f, 0.f, 0.f, 0.f};
        int row = r0b + r;
        if (row < N) {
            v = ((const float4*)(X + (size_t)row * 128))[kq];
            if (MODE >= 1) {
                float4 sc = *(const float4*)&scale[4 * kq];
                float4 sh = *(const float4*)&shift[4 * kq];
                v.x = fmaxf(v.x * sc.x + sh.x, 0.f);
                v.y = fmaxf(v.y * sc.y + sh.y, 0.f);
                v.z = fmaxf(v.z * sc.z + sh.z, 0.f);
                v.w = fmaxf(v.w * sc.w + sh.w, 0.f);
                if (MODE == 1) {
                    ushort4 o;
                    o.x = bf16rne(v.x); o.y = bf16rne(v.y);
                    o.z = bf16rne(v.z); o.w = bf16rne(v.w);
                    *(ushort4*)&x1buf[(size_t)row * 128 + 4 * kq] = o;
                } else {
                    ushort4 s4 = *(const ushort4*)&x1buf[(size_t)row * 128 + 4 * kq];
                    v.x += bf16tof(s4.x); v.y += bf16tof(s4.y);
                    v.z += bf16tof(s4.z); v.w += bf16tof(s4.w);
                }
            }
        }
        XsT[(4 * kq + 0) * ROWS + r] = v.x;
        XsT[(4 * kq + 1) * ROWS + r] = v.y;
        XsT[(4 * kq + 2) * ROWS + r] = v.z;
        XsT[(4 * kq + 3) * ROWS + r] = v.w;
    }
    __syncthreads();

    int c = t % CG, rg = t / CG;
    int j0 = c * 4, r0 = rg * 4;
    float4 a0 = {0,0,0,0}, a1 = {0,0,0,0}, a2 = {0,0,0,0}, a3 = {0,0,0,0};

#pragma unroll 8
    for (int k = 0; k < 128; ++k) {
        float4 wv = *(const float4*)&Ws[k * M + j0];
        float4 xv = *(const float4*)&XsT[k * ROWS + r0];
        a0.x += xv.x * wv.x; a0.y += xv.x * wv.y; a0.z += xv.x * wv.z; a0.w += xv.x * wv.w;
        a1.x += xv.y * wv.x; a1.y += xv.y * wv.y; a1.z += xv.y * wv.z; a1.w += xv.y * wv.w;
        a2.x += xv.z * wv.x; a2.y += xv.z * wv.y; a2.z += xv.z * wv.z; a2.w += xv.z * wv.w;
        a3.x += xv.w * wv.x; a3.y += xv.w * wv.y; a3.z += xv.w * wv.z; a3.w += xv.w * wv.w;
    }

    float4 accs[4] = {a0, a1, a2, a3};
#pragma unroll
    for (int i = 0; i < 4; ++i) {
        int row = r0b + r0 + i;
        if (row < N) {
            ushort4 o;
            o.x = bf16rne(accs[i].x); o.y = bf16rne(accs[i].y);
            o.z = bf16rne(accs[i].z); o.w = bf16rne(accs[i].w);
            *(ushort4*)&Hout[(size_t)row * M + j0] = o;
        }
    }
}

// ---------------- Aggregation (bf16 gather, fp32 accumulate) ----------------
// out = (sum_e dinv[src_e]*h[src_e] + h[i]*di) * di + bias
// STATS: fused BN column sums (sum, sumsq) into 32-way-spread accumulators.

template<int M, bool STATS>
__global__ __launch_bounds__(256) void k_agg(const ushort_t* __restrict__ Hm,
                      const int* __restrict__ rowptr,
                      const int* __restrict__ csr_src, const float* __restrict__ dinv,
                      const float* __restrict__ bias, float* __restrict__ Out, int N,
                      float* __restrict__ spread) {
    constexpr int TPN = M / 8;           // threads per node
    constexpr int NPB = 256 / TPN;       // nodes per block
    int li = threadIdx.x / TPN;
    int lane = threadIdx.x % TPN;
    int i = blockIdx.x * NPB + li;
    bool valid = (i < N);
    int j0 = lane * 8;

    float o[8] = {0.f, 0.f, 0.f, 0.f, 0.f, 0.f, 0.f, 0.f};

    if (valid) {
        int p = rowptr[i], p1 = rowptr[i + 1];
        for (; p + 3 < p1; p += 4) {
            int s0 = csr_src[p + 0];
            int s1 = csr_src[p + 1];
            int s2 = csr_src[p + 2];
            int s3 = csr_src[p + 3];
            float c0 = dinv[s0], c1 = dinv[s1], c2 = dinv[s2], c3 = dinv[s3];
            uint4 g0 = *(const uint4*)&Hm[(size_t)s0 * M + j0];
            uint4 g1 = *(const uint4*)&Hm[(size_t)s1 * M + j0];
            uint4 g2 = *(const uint4*)&Hm[(size_t)s2 * M + j0];
            uint4 g3 = *(const uint4*)&Hm[(size_t)s3 * M + j0];
            float lo, hi;
            cvt2(g0.x, lo, hi); o[0] += lo * c0; o[1] += hi * c0;
            cvt2(g0.y, lo, hi); o[2] += lo * c0; o[3] += hi * c0;
            cvt2(g0.z, lo, hi); o[4] += lo * c0; o[5] += hi * c0;
            cvt2(g0.w, lo, hi); o[6] += lo * c0; o[7] += hi * c0;
            cvt2(g1.x, lo, hi); o[0] += lo * c1; o[1] += hi * c1;
            cvt2(g1.y, lo, hi); o[2] += lo * c1; o[3] += hi * c1;
            cvt2(g1.z, lo, hi); o[4] += lo * c1; o[5] += hi * c1;
            cvt2(g1.w, lo, hi); o[6] += lo * c1; o[7] += hi * c1;
            cvt2(g2.x, lo, hi); o[0] += lo * c2; o[1] += hi * c2;
            cvt2(g2.y, lo, hi); o[2] += lo * c2; o[3] += hi * c2;
            cvt2(g2.z, lo, hi); o[4] += lo * c2; o[5] += hi * c2;
            cvt2(g2.w, lo, hi); o[6] += lo * c2; o[7] += hi * c2;
            cvt2(g3.x, lo, hi); o[0] += lo * c3; o[1] += hi * c3;
            cvt2(g3.y, lo, hi); o[2] += lo * c3; o[3] += hi * c3;
            cvt2(g3.z, lo, hi); o[4] += lo * c3; o[5] += hi * c3;
            cvt2(g3.w, lo, hi); o[6] += lo * c3; o[7] += hi * c3;
        }
        for (; p < p1; ++p) {
            int s = csr_src[p];
            float cf = dinv[s];
            uint4 g = *(const uint4*)&Hm[(size_t)s * M + j0];
            float lo, hi;
            cvt2(g.x, lo, hi); o[0] += lo * cf; o[1] += hi * cf;
            cvt2(g.y, lo, hi); o[2] += lo * cf; o[3] += hi * cf;
            cvt2(g.z, lo, hi); o[4] += lo * cf; o[5] += hi * cf;
            cvt2(g.w, lo, hi); o[6] += lo * cf; o[7] += hi * cf;
        }

        float di = dinv[i];
        uint4 hs = *(const uint4*)&Hm[(size_t)i * M + j0];
        float lo, hi;
        cvt2(hs.x, lo, hi); o[0] += lo * di; o[1] += hi * di;
        cvt2(hs.y, lo, hi); o[2] += lo * di; o[3] += hi * di;
        cvt2(hs.z, lo, hi); o[4] += lo * di; o[5] += hi * di;
        cvt2(hs.w, lo, hi); o[6] += lo * di; o[7] += hi * di;

        float4 bv0 = *(const float4*)&bias[j0];
        float4 bv1 = *(const float4*)&bias[j0 + 4];
        o[0] = o[0] * di + bv0.x; o[1] = o[1] * di + bv0.y;
        o[2] = o[2] * di + bv0.z; o[3] = o[3] * di + bv0.w;
        o[4] = o[4] * di + bv1.x; o[5] = o[5] * di + bv1.y;
        o[6] = o[6] * di + bv1.z; o[7] = o[7] * di + bv1.w;
    }

    if constexpr (STATS) {
        // per-thread 16 stat values: sums then squares
        float st[16];
#pragma unroll
        for (int k = 0; k < 8; ++k) { st[k] = o[k]; st[8 + k] = o[k] * o[k]; }
        // reduce over the 4 nodes within each wave (lane bits 4,5)
#pragma unroll
        for (int k = 0; k < 16; ++k) {
            st[k] += __shfl_xor(st[k], 16);
            st[k] += __shfl_xor(st[k], 32);
        }
        __shared__ float red[4][16][16];
        int wv = threadIdx.x >> 6;
        int ln = threadIdx.x & 63;
        if (ln < 16) {
#pragma unroll
            for (int k = 0; k < 16; ++k) red[wv][ln][k] = st[k];
        }
        __syncthreads();
        if (threadIdx.x < 16) {
            int cg = threadIdx.x;
            int w = (blockIdx.x & 31);
#pragma unroll
            for (int k = 0; k < 16; ++k) {
                float s = red[0][cg][k] + red[1][cg][k] + red[2][cg][k] + red[3][cg][k];
                int j = cg * 8 + (k & 7);
                float* dst = (k < 8) ? &spread[w * 128 + j]
                                     : &spread[32 * 128 + w * 128 + j];
                atomicAdd(dst, s);
            }
        }
    }

    if (valid) {
        float4 o0 = {o[0], o[1], o[2], o[3]};
        float4 o1 = {o[4], o[5], o[6], o[7]};
        *(float4*)&Out[(size_t)i * M + j0] = o0;
        *(float4*)&Out[(size_t)i * M + j0 + 4] = o1;
    }
}

// ---------------- launch ----------------

extern "C" void kernel_launch(void* const* d_in, const int* in_sizes, int n_in,
                              void* d_out, int out_size, void* d_ws, size_t ws_size,
                              hipStream_t stream) {
    const float* x   = (const float*)d_in[0];
    const int*   ei  = (const int*)d_in[1];
    const float* W1  = (const float*)d_in[2];
    const float* b1  = (const float*)d_in[3];
    const float* g1  = (const float*)d_in[4];
    const float* be1 = (const float*)d_in[5];
    const float* W2  = (const float*)d_in[6];
    const float* b2  = (const float*)d_in[7];
    const float* g2  = (const float*)d_in[8];
    const float* be2 = (const float*)d_in[9];
    const float* W3  = (const float*)d_in[10];
    const float* b3  = (const float*)d_in[11];

    int N = in_sizes[0] / 128;
    int E = in_sizes[1] / 2;
    const int* srcp = ei;
    const int* dstp = ei + E;

    char* ws = (char*)d_ws;
    size_t off = 0;
    auto alloc = [&](size_t bytes) {
        void* p = ws + off;
        off += (bytes + 255) & ~(size_t)255;
        return p;
    };

    int*   counts   = (int*)alloc((size_t)N * 4);
    int*   rowptr   = (int*)alloc(((size_t)N + 1) * 4);
    int*   cursor   = (int*)alloc((size_t)N * 4);
    int*   blockTot = (int*)alloc(512 * 4);
    int*   csr_src  = (int*)alloc((size_t)E * 4);
    float* dinv     = (float*)alloc((size_t)N * 4);
    float* spreadA  = (float*)alloc(2 * 32 * 128 * 4);
    float* spreadB  = (float*)alloc(2 * 32 * 128 * 4);
    float* scale1   = (float*)alloc(128 * 4);
    float* shift1   = (float*)alloc(128 * 4);
    float* scale2   = (float*)alloc(128 * 4);
    float* shift2   = (float*)alloc(128 * 4);
    ushort_t* hbuf  = (ushort_t*)alloc((size_t)N * 128 * 2);  // bf16 h-table
    ushort_t* x1bf  = (ushort_t*)alloc((size_t)N * 128 * 2);  // bf16 x1 (skip)
    float* buf1 = (float*)alloc((size_t)N * 128 * 4);         // a1 (agg1 out)
    float* buf2 = (float*)alloc((size_t)N * 128 * 4);         // a2 (agg2 out)
    float* outp = (float*)d_out;

    int nb1 = (N + 255) / 256;
    float invN = 1.0f / (float)N;

    // CSR build + dinv
    hipMemsetAsync(counts, 0, (size_t)N * 4, stream);
    k_count<<<(E + 255) / 256, 256, 0, stream>>>(dstp, E, counts);
    k_scan1<<<nb1, 256, 0, stream>>>(counts, N, rowptr, blockTot);
    k_scan2<<<1, 512, 0, stream>>>(blockTot, nb1);
    k_scan3<<<nb1, 256, 0, stream>>>(counts, N, E, rowptr, blockTot, cursor, dinv);
    k_fill<<<(E + 255) / 256, 256, 0, stream>>>(srcp, dstp, E, cursor, csr_src);
    hipMemsetAsync(spreadA, 0, 2 * 32 * 128 * 4, stream);
    hipMemsetAsync(spreadB, 0, 2 * 32 * 128 * 4, stream);

    // layer 1: h = x@W1 ; a1 = agg(h) + stats
    k_gemm<128, 32, 0><<<(N + 31) / 32, 256, 0, stream>>>(x, W1, hbuf, N,
                                                          nullptr, nullptr, nullptr);
    k_agg<128, true><<<(N + 15) / 16, 256, 0, stream>>>(hbuf, rowptr, csr_src, dinv,
                                                        b1, buf1, N, spreadA);
    k_bnparam<<<1, 128, 0, stream>>>(spreadA, g1, be1, scale1, shift1, invN);

    // layer 2: h = relu(bn1(a1))@W2 (x1 written bf16) ; a2 = agg(h) + stats
    k_gemm<128, 32, 1><<<(N + 31) / 32, 256, 0, stream>>>(buf1, W2, hbuf, N,
                                                          scale1, shift1, x1bf);
    k_agg<128, true><<<(N + 15) / 16, 256, 0, stream>>>(hbuf, rowptr, csr_src, dinv,
                                                        b2, buf2, N, spreadB);
    k_bnparam<<<1, 128, 0, stream>>>(spreadB, g2, be2, scale2, shift2, invN);

    // layer 3: h = (relu(bn2(a2)) + x1)@W3 ; out = agg(h)
    k_gemm<64, 64, 2><<<(N + 63) / 64, 256, 0, stream>>>(buf2, W3, hbuf, N,
                                                         scale2, shift2, x1bf);
    k_agg<64, false><<<(N + 31) / 32, 256, 0, stream>>>(hbuf, rowptr, csr_src, dinv,
                                                        b3, outp, N, nullptr);
}

// Round 6
// 516.497 us; speedup vs baseline: 2.4330x; 1.2108x over previous
//
#include <hip/hip_runtime.h>

#define BN_EPS 1e-5f

typedef unsigned short ushort_t;

// round-to-nearest-even fp32 -> bf16 (finite inputs)
__device__ __forceinline__ ushort_t bf16rne(float f) {
    unsigned int u = __float_as_uint(f);
    unsigned int r = (u + 0x7FFFu + ((u >> 16) & 1u)) >> 16;
    return (ushort_t)r;
}
__device__ __forceinline__ float bf16tof(ushort_t u) {
    return __uint_as_float(((unsigned int)u) << 16);
}
// u32 holding two packed bf16 -> two floats
__device__ __forceinline__ void cvt2(unsigned int u, float& lo, float& hi) {
    lo = __uint_as_float(u << 16);
    hi = __uint_as_float(u & 0xFFFF0000u);
}

// ---------------- CSR build: locality-aware 2-pass counting sort ----------------
// Buckets of 256 consecutive dst nodes. NB = ceil(N/256) <= 512.

#define BIN_CHUNK 4096

// Per-WG LDS histogram of buckets -> few global atomics.
__global__ __launch_bounds__(256) void k_binhist(const int* __restrict__ dst, int E, int NB,
                                                 int* __restrict__ bucket_counts) {
    __shared__ int hist[512];
    for (int i = threadIdx.x; i < NB; i += 256) hist[i] = 0;
    __syncthreads();
    int base = blockIdx.x * BIN_CHUNK;
    int end = min(E, base + BIN_CHUNK);
    for (int e = base + threadIdx.x; e < end; e += 256)
        atomicAdd(&hist[dst[e] >> 8], 1);
    __syncthreads();
    for (int i = threadIdx.x; i < NB; i += 256)
        if (hist[i]) atomicAdd(&bucket_counts[i], hist[i]);
}

// Exclusive scan of bucket counts -> bucket_base, bucket_cursor; rowptr[N]=E.
__global__ void k_bucketscan(const int* __restrict__ bucket_counts, int NB, int N, int E,
                             int* __restrict__ bucket_base, int* __restrict__ bucket_cursor,
                             int* __restrict__ rowptr) {
    __shared__ int sh[512];
    int t = threadIdx.x;
    int v = (t < NB) ? bucket_counts[t] : 0;
    sh[t] = v;
    __syncthreads();
    for (int off = 1; off < 512; off <<= 1) {
        int x = (t >= off) ? sh[t - off] : 0;
        __syncthreads();
        sh[t] += x;
        __syncthreads();
    }
    if (t < NB) {
        int b = sh[t] - v;
        bucket_base[t] = b;
        bucket_cursor[t] = b;
    }
    if (t == 0) { bucket_base[NB] = E; rowptr[N] = E; }
}

// Scatter (src,dst) pairs into bucket-contiguous regions.
__global__ __launch_bounds__(256) void k_bin(const int* __restrict__ src,
                                             const int* __restrict__ dst, int E, int NB,
                                             int* __restrict__ bucket_cursor,
                                             int2* __restrict__ binned) {
    __shared__ int hist[512];
    __shared__ int cur[512];
    for (int i = threadIdx.x; i < NB; i += 256) hist[i] = 0;
    __syncthreads();
    int base = blockIdx.x * BIN_CHUNK;
    int end = min(E, base + BIN_CHUNK);
    for (int e = base + threadIdx.x; e < end; e += 256)
        atomicAdd(&hist[dst[e] >> 8], 1);
    __syncthreads();
    for (int i = threadIdx.x; i < NB; i += 256)
        cur[i] = hist[i] ? atomicAdd(&bucket_cursor[i], hist[i]) : 0;
    __syncthreads();
    for (int e = base + threadIdx.x; e < end; e += 256) {
        int d = dst[e];
        int pos = atomicAdd(&cur[d >> 8], 1);
        binned[pos] = make_int2(src[e], d);
    }
}

// Per-bucket finalize: per-node counts -> rowptr, dinv, csr_src (contiguous region).
__global__ __launch_bounds__(256) void k_bucket(const int2* __restrict__ binned,
                                                const int* __restrict__ bucket_base, int N,
                                                int* __restrict__ rowptr,
                                                float* __restrict__ dinv,
                                                int* __restrict__ csr_src) {
    __shared__ int cnt[256];
    __shared__ int sh[256];
    __shared__ int cur[256];
    int b = blockIdx.x;
    int t = threadIdx.x;
    int node0 = b << 8;
    int lo = bucket_base[b], hi = bucket_base[b + 1];
    cnt[t] = 0;
    __syncthreads();
    for (int p = lo + t; p < hi; p += 256) {
        int2 pr = binned[p];
        atomicAdd(&cnt[pr.y & 255], 1);
    }
    __syncthreads();
    int v = cnt[t];
    sh[t] = v;
    __syncthreads();
    for (int off = 1; off < 256; off <<= 1) {
        int y = (t >= off) ? sh[t - off] : 0;
        __syncthreads();
        sh[t] += y;
        __syncthreads();
    }
    int gbase = lo + (sh[t] - v);
    int node = node0 + t;
    if (node < N) {
        rowptr[node] = gbase;
        dinv[node] = rsqrtf((float)v + 1.0f);   // deg = in-degree + self-loop
    }
    cur[t] = gbase;
    __syncthreads();
    for (int p = lo + t; p < hi; p += 256) {
        int2 pr = binned[p];
        int pos = atomicAdd(&cur[pr.y & 255], 1);
        csr_src[pos] = pr.x;
    }
}

// ---------------- BN params: scale/shift from spread stats ----------------
// spread layout: [0][32][128] = colsum partials, [1][32][128] = colsq partials

__global__ void k_bnparam(const float* __restrict__ sp, const float* __restrict__ g,
                          const float* __restrict__ be, float* __restrict__ scale,
                          float* __restrict__ shift, float invN) {
    int j = threadIdx.x;  // 128 threads
    float s = 0.f, q = 0.f;
#pragma unroll
    for (int w = 0; w < 32; ++w) {
        s += sp[w * 128 + j];
        q += sp[32 * 128 + w * 128 + j];
    }
    float m = s * invN;
    float var = q * invN - m * m;
    float r = rsqrtf(var + BN_EPS);
    float sc = g[j] * r;
    scale[j] = sc;
    shift[j] = be[j] - m * sc;
}

// ---------------- GEMM: Hout[N,M](bf16) = f(X)[N,128] @ W[128,M] ----------------
// MODE 0: f = identity
// MODE 1: f = relu(X*scale+shift), also writes f(X) to x1buf (bf16)
// MODE 2: f = relu(X*scale+shift) + bf16(x1buf)

template<int M, int ROWS, int MODE>
__global__ __launch_bounds__(256) void k_gemm(const float* __restrict__ X,
                                              const float* __restrict__ W,
                                              ushort_t* __restrict__ Hout, int N,
                                              const float* __restrict__ scale,
                                              const float* __restrict__ shift,
                                              ushort_t* __restrict__ x1buf) {
    __shared__ float Ws[128 * M];
    __shared__ float XsT[128 * ROWS];
    constexpr int CG = M / 4;
    constexpr int RG = 256 / CG;
    static_assert(ROWS / RG == 4, "4 rows per thread");

    int t = threadIdx.x;
    int r0b = blockIdx.x * ROWS;

    for (int i4 = t; i4 < 32 * M; i4 += 256)
        ((float4*)Ws)[i4] = ((const float4*)W)[i4];

    for (int idx = t; idx < ROWS * 32; idx += 256) {
        int r = idx >> 5, kq = idx & 31;
        float4 v = {0.f, 0.f, 0.f, 0.f};
        int row = r0b + r;
        if (row < N) {
            v = ((const float4*)(X + (size_t)row * 128))[kq];
            if (MODE >= 1) {
                float4 sc = *(const float4*)&scale[4 * kq];
                float4 sh = *(const float4*)&shift[4 * kq];
                v.x = fmaxf(v.x * sc.x + sh.x, 0.f);
                v.y = fmaxf(v.y * sc.y + sh.y, 0.f);
                v.z = fmaxf(v.z * sc.z + sh.z, 0.f);
                v.w = fmaxf(v.w * sc.w + sh.w, 0.f);
                if (MODE == 1) {
                    ushort4 o;
                    o.x = bf16rne(v.x); o.y = bf16rne(v.y);
                    o.z = bf16rne(v.z); o.w = bf16rne(v.w);
                    *(ushort4*)&x1buf[(size_t)row * 128 + 4 * kq] = o;
                } else {
                    ushort4 s4 = *(const ushort4*)&x1buf[(size_t)row * 128 + 4 * kq];
                    v.x += bf16tof(s4.x); v.y += bf16tof(s4.y);
                    v.z += bf16tof(s4.z); v.w += bf16tof(s4.w);
                }
            }
        }
        XsT[(4 * kq + 0) * ROWS + r] = v.x;
        XsT[(4 * kq + 1) * ROWS + r] = v.y;
        XsT[(4 * kq + 2) * ROWS + r] = v.z;
        XsT[(4 * kq + 3) * ROWS + r] = v.w;
    }
    __syncthreads();

    int c = t % CG, rg = t / CG;
    int j0 = c * 4, r0 = rg * 4;
    float4 a0 = {0,0,0,0}, a1 = {0,0,0,0}, a2 = {0,0,0,0}, a3 = {0,0,0,0};

#pragma unroll 8
    for (int k = 0; k < 128; ++k) {
        float4 wv = *(const float4*)&Ws[k * M + j0];
        float4 xv = *(const float4*)&XsT[k * ROWS + r0];
        a0.x += xv.x * wv.x; a0.y += xv.x * wv.y; a0.z += xv.x * wv.z; a0.w += xv.x * wv.w;
        a1.x += xv.y * wv.x; a1.y += xv.y * wv.y; a1.z += xv.y * wv.z; a1.w += xv.y * wv.w;
        a2.x += xv.z * wv.x; a2.y += xv.z * wv.y; a2.z += xv.z * wv.z; a2.w += xv.z * wv.w;
        a3.x += xv.w * wv.x; a3.y += xv.w * wv.y; a3.z += xv.w * wv.z; a3.w += xv.w * wv.w;
    }

    float4 accs[4] = {a0, a1, a2, a3};
#pragma unroll
    for (int i = 0; i < 4; ++i) {
        int row = r0b + r0 + i;
        if (row < N) {
            ushort4 o;
            o.x = bf16rne(accs[i].x); o.y = bf16rne(accs[i].y);
            o.z = bf16rne(accs[i].z); o.w = bf16rne(accs[i].w);
            *(ushort4*)&Hout[(size_t)row * M + j0] = o;
        }
    }
}

// ---------------- Aggregation (bf16 gather, fp32 accumulate) ----------------
// out = (sum_e dinv[src_e]*h[src_e] + h[i]*di) * di + bias
// STATS: fused BN column sums (sum, sumsq) into 32-way-spread accumulators.

template<int M, bool STATS>
__global__ __launch_bounds__(256) void k_agg(const ushort_t* __restrict__ Hm,
                      const int* __restrict__ rowptr,
                      const int* __restrict__ csr_src, const float* __restrict__ dinv,
                      const float* __restrict__ bias, float* __restrict__ Out, int N,
                      float* __restrict__ spread) {
    constexpr int TPN = M / 8;           // threads per node
    constexpr int NPB = 256 / TPN;       // nodes per block
    int li = threadIdx.x / TPN;
    int lane = threadIdx.x % TPN;
    int i = blockIdx.x * NPB + li;
    bool valid = (i < N);
    int j0 = lane * 8;

    float o[8] = {0.f, 0.f, 0.f, 0.f, 0.f, 0.f, 0.f, 0.f};

    if (valid) {
        int p = rowptr[i], p1 = rowptr[i + 1];
        for (; p + 3 < p1; p += 4) {
            int s0 = csr_src[p + 0];
            int s1 = csr_src[p + 1];
            int s2 = csr_src[p + 2];
            int s3 = csr_src[p + 3];
            float c0 = dinv[s0], c1 = dinv[s1], c2 = dinv[s2], c3 = dinv[s3];
            uint4 g0 = *(const uint4*)&Hm[(size_t)s0 * M + j0];
            uint4 g1 = *(const uint4*)&Hm[(size_t)s1 * M + j0];
            uint4 g2 = *(const uint4*)&Hm[(size_t)s2 * M + j0];
            uint4 g3 = *(const uint4*)&Hm[(size_t)s3 * M + j0];
            float lo, hi;
            cvt2(g0.x, lo, hi); o[0] += lo * c0; o[1] += hi * c0;
            cvt2(g0.y, lo, hi); o[2] += lo * c0; o[3] += hi * c0;
            cvt2(g0.z, lo, hi); o[4] += lo * c0; o[5] += hi * c0;
            cvt2(g0.w, lo, hi); o[6] += lo * c0; o[7] += hi * c0;
            cvt2(g1.x, lo, hi); o[0] += lo * c1; o[1] += hi * c1;
            cvt2(g1.y, lo, hi); o[2] += lo * c1; o[3] += hi * c1;
            cvt2(g1.z, lo, hi); o[4] += lo * c1; o[5] += hi * c1;
            cvt2(g1.w, lo, hi); o[6] += lo * c1; o[7] += hi * c1;
            cvt2(g2.x, lo, hi); o[0] += lo * c2; o[1] += hi * c2;
            cvt2(g2.y, lo, hi); o[2] += lo * c2; o[3] += hi * c2;
            cvt2(g2.z, lo, hi); o[4] += lo * c2; o[5] += hi * c2;
            cvt2(g2.w, lo, hi); o[6] += lo * c2; o[7] += hi * c2;
            cvt2(g3.x, lo, hi); o[0] += lo * c3; o[1] += hi * c3;
            cvt2(g3.y, lo, hi); o[2] += lo * c3; o[3] += hi * c3;
            cvt2(g3.z, lo, hi); o[4] += lo * c3; o[5] += hi * c3;
            cvt2(g3.w, lo, hi); o[6] += lo * c3; o[7] += hi * c3;
        }
        for (; p < p1; ++p) {
            int s = csr_src[p];
            float cf = dinv[s];
            uint4 g = *(const uint4*)&Hm[(size_t)s * M + j0];
            float lo, hi;
            cvt2(g.x, lo, hi); o[0] += lo * cf; o[1] += hi * cf;
            cvt2(g.y, lo, hi); o[2] += lo * cf; o[3] += hi * cf;
            cvt2(g.z, lo, hi); o[4] += lo * cf; o[5] += hi * cf;
            cvt2(g.w, lo, hi); o[6] += lo * cf; o[7] += hi * cf;
        }

        float di = dinv[i];
        uint4 hs = *(const uint4*)&Hm[(size_t)i * M + j0];
        float lo, hi;
        cvt2(hs.x, lo, hi); o[0] += lo * di; o[1] += hi * di;
        cvt2(hs.y, lo, hi); o[2] += lo * di; o[3] += hi * di;
        cvt2(hs.z, lo, hi); o[4] += lo * di; o[5] += hi * di;
        cvt2(hs.w, lo, hi); o[6] += lo * di; o[7] += hi * di;

        float4 bv0 = *(const float4*)&bias[j0];
        float4 bv1 = *(const float4*)&bias[j0 + 4];
        o[0] = o[0] * di + bv0.x; o[1] = o[1] * di + bv0.y;
        o[2] = o[2] * di + bv0.z; o[3] = o[3] * di + bv0.w;
        o[4] = o[4] * di + bv1.x; o[5] = o[5] * di + bv1.y;
        o[6] = o[6] * di + bv1.z; o[7] = o[7] * di + bv1.w;
    }

    if constexpr (STATS) {
        float st[16];
#pragma unroll
        for (int k = 0; k < 8; ++k) { st[k] = o[k]; st[8 + k] = o[k] * o[k]; }
#pragma unroll
        for (int k = 0; k < 16; ++k) {
            st[k] += __shfl_xor(st[k], 16);
            st[k] += __shfl_xor(st[k], 32);
        }
        __shared__ float red[4][16][16];
        int wv = threadIdx.x >> 6;
        int ln = threadIdx.x & 63;
        if (ln < 16) {
#pragma unroll
            for (int k = 0; k < 16; ++k) red[wv][ln][k] = st[k];
        }
        __syncthreads();
        if (threadIdx.x < 16) {
            int cg = threadIdx.x;
            int w = (blockIdx.x & 31);
#pragma unroll
            for (int k = 0; k < 16; ++k) {
                float s = red[0][cg][k] + red[1][cg][k] + red[2][cg][k] + red[3][cg][k];
                int j = cg * 8 + (k & 7);
                float* dst = (k < 8) ? &spread[w * 128 + j]
                                     : &spread[32 * 128 + w * 128 + j];
                atomicAdd(dst, s);
            }
        }
    }

    if (valid) {
        float4 o0 = {o[0], o[1], o[2], o[3]};
        float4 o1 = {o[4], o[5], o[6], o[7]};
        *(float4*)&Out[(size_t)i * M + j0] = o0;
        *(float4*)&Out[(size_t)i * M + j0 + 4] = o1;
    }
}

// ---------------- launch ----------------

extern "C" void kernel_launch(void* const* d_in, const int* in_sizes, int n_in,
                              void* d_out, int out_size, void* d_ws, size_t ws_size,
                              hipStream_t stream) {
    const float* x   = (const float*)d_in[0];
    const int*   ei  = (const int*)d_in[1];
    const float* W1  = (const float*)d_in[2];
    const float* b1  = (const float*)d_in[3];
    const float* g1  = (const float*)d_in[4];
    const float* be1 = (const float*)d_in[5];
    const float* W2  = (const float*)d_in[6];
    const float* b2  = (const float*)d_in[7];
    const float* g2  = (const float*)d_in[8];
    const float* be2 = (const float*)d_in[9];
    const float* W3  = (const float*)d_in[10];
    const float* b3  = (const float*)d_in[11];

    int N = in_sizes[0] / 128;
    int E = in_sizes[1] / 2;
    const int* srcp = ei;
    const int* dstp = ei + E;
    int NB = (N + 255) >> 8;          // buckets of 256 nodes (<=512)

    char* ws = (char*)d_ws;
    size_t off = 0;
    auto alloc = [&](size_t bytes) {
        void* p = ws + off;
        off += (bytes + 255) & ~(size_t)255;
        return p;
    };

    int*   rowptr   = (int*)alloc(((size_t)N + 1) * 4);
    int*   csr_src  = (int*)alloc((size_t)E * 4);
    float* dinv     = (float*)alloc((size_t)N * 4);
    int*   bucket_counts = (int*)alloc(512 * 4);
    int*   bucket_base   = (int*)alloc(513 * 4);
    int*   bucket_cursor = (int*)alloc(512 * 4);
    float* spreadA  = (float*)alloc(2 * 32 * 128 * 4);
    float* spreadB  = (float*)alloc(2 * 32 * 128 * 4);
    float* scale1   = (float*)alloc(128 * 4);
    float* shift1   = (float*)alloc(128 * 4);
    float* scale2   = (float*)alloc(128 * 4);
    float* shift2   = (float*)alloc(128 * 4);
    ushort_t* hbuf  = (ushort_t*)alloc((size_t)N * 128 * 2);  // bf16 h-table
    ushort_t* x1bf  = (ushort_t*)alloc((size_t)N * 128 * 2);  // bf16 x1 (skip)
    float* buf1 = (float*)alloc((size_t)N * 128 * 4);         // a1 (agg1 out)
    float* buf2 = (float*)alloc((size_t)N * 128 * 4);         // a2 (agg2 out)
    float* outp = (float*)d_out;
    int2*  binned = (int2*)buf1;   // alias: binned dead before buf1 first written

    float invN = 1.0f / (float)N;
    int nbE = (E + BIN_CHUNK - 1) / BIN_CHUNK;

    // CSR build (2-pass counting sort)
    hipMemsetAsync(bucket_counts, 0, 512 * 4, stream);
    k_binhist<<<nbE, 256, 0, stream>>>(dstp, E, NB, bucket_counts);
    k_bucketscan<<<1, 512, 0, stream>>>(bucket_counts, NB, N, E,
                                        bucket_base, bucket_cursor, rowptr);
    k_bin<<<nbE, 256, 0, stream>>>(srcp, dstp, E, NB, bucket_cursor, binned);
    k_bucket<<<NB, 256, 0, stream>>>(binned, bucket_base, N, rowptr, dinv, csr_src);
    hipMemsetAsync(spreadA, 0, 2 * 32 * 128 * 4, stream);
    hipMemsetAsync(spreadB, 0, 2 * 32 * 128 * 4, stream);

    // layer 1: h = x@W1 ; a1 = agg(h) + stats
    k_gemm<128, 32, 0><<<(N + 31) / 32, 256, 0, stream>>>(x, W1, hbuf, N,
                                                          nullptr, nullptr, nullptr);
    k_agg<128, true><<<(N + 15) / 16, 256, 0, stream>>>(hbuf, rowptr, csr_src, dinv,
                                                        b1, buf1, N, spreadA);
    k_bnparam<<<1, 128, 0, stream>>>(spreadA, g1, be1, scale1, shift1, invN);

    // layer 2: h = relu(bn1(a1))@W2 (x1 written bf16) ; a2 = agg(h) + stats
    k_gemm<128, 32, 1><<<(N + 31) / 32, 256, 0, stream>>>(buf1, W2, hbuf, N,
                                                          scale1, shift1, x1bf);
    k_agg<128, true><<<(N + 15) / 16, 256, 0, stream>>>(hbuf, rowptr, csr_src, dinv,
                                                        b2, buf2, N, spreadB);
    k_bnparam<<<1, 128, 0, stream>>>(spreadB, g2, be2, scale2, shift2, invN);

    // layer 3: h = (relu(bn2(a2)) + x1)@W3 ; out = agg(h)
    k_gemm<64, 64, 2><<<(N + 63) / 64, 256, 0, stream>>>(buf2, W3, hbuf, N,
                                                         scale2, shift2, x1bf);
    k_agg<64, false><<<(N + 31) / 32, 256, 0, stream>>>(hbuf, rowptr, csr_src, dinv,
                                                        b3, outp, N, nullptr);
}

// Round 7
// 470.270 us; speedup vs baseline: 2.6722x; 1.0983x over previous
//
#include <hip/hip_runtime.h>

#define BN_EPS 1e-5f

typedef unsigned short ushort_t;

// round-to-nearest-even fp32 -> bf16 (finite inputs)
__device__ __forceinline__ ushort_t bf16rne(float f) {
    unsigned int u = __float_as_uint(f);
    unsigned int r = (u + 0x7FFFu + ((u >> 16) & 1u)) >> 16;
    return (ushort_t)r;
}
__device__ __forceinline__ unsigned int pack2(float a, float b) {
    return (unsigned int)bf16rne(a) | ((unsigned int)bf16rne(b) << 16);
}
// u32 holding two packed bf16 -> two floats
__device__ __forceinline__ void cvt2(unsigned int u, float& lo, float& hi) {
    lo = __uint_as_float(u << 16);
    hi = __uint_as_float(u & 0xFFFF0000u);
}

// ---------------- CSR build: locality-aware 2-pass counting sort ----------------

#define BIN_CHUNK 4096

__global__ __launch_bounds__(256) void k_binhist(const int* __restrict__ dst, int E, int NB,
                                                 int* __restrict__ bucket_counts) {
    __shared__ int hist[512];
    for (int i = threadIdx.x; i < NB; i += 256) hist[i] = 0;
    __syncthreads();
    int base = blockIdx.x * BIN_CHUNK;
    int end = min(E, base + BIN_CHUNK);
    for (int e = base + threadIdx.x; e < end; e += 256)
        atomicAdd(&hist[dst[e] >> 8], 1);
    __syncthreads();
    for (int i = threadIdx.x; i < NB; i += 256)
        if (hist[i]) atomicAdd(&bucket_counts[i], hist[i]);
}

__global__ void k_bucketscan(const int* __restrict__ bucket_counts, int NB, int N, int E,
                             int* __restrict__ bucket_base, int* __restrict__ bucket_cursor,
                             int* __restrict__ rowptr) {
    __shared__ int sh[512];
    int t = threadIdx.x;
    int v = (t < NB) ? bucket_counts[t] : 0;
    sh[t] = v;
    __syncthreads();
    for (int off = 1; off < 512; off <<= 1) {
        int x = (t >= off) ? sh[t - off] : 0;
        __syncthreads();
        sh[t] += x;
        __syncthreads();
    }
    if (t < NB) {
        int b = sh[t] - v;
        bucket_base[t] = b;
        bucket_cursor[t] = b;
    }
    if (t == 0) { bucket_base[NB] = E; rowptr[N] = E; }
}

__global__ __launch_bounds__(256) void k_bin(const int* __restrict__ src,
                                             const int* __restrict__ dst, int E, int NB,
                                             int* __restrict__ bucket_cursor,
                                             int2* __restrict__ binned) {
    __shared__ int hist[512];
    __shared__ int cur[512];
    for (int i = threadIdx.x; i < NB; i += 256) hist[i] = 0;
    __syncthreads();
    int base = blockIdx.x * BIN_CHUNK;
    int end = min(E, base + BIN_CHUNK);
    for (int e = base + threadIdx.x; e < end; e += 256)
        atomicAdd(&hist[dst[e] >> 8], 1);
    __syncthreads();
    for (int i = threadIdx.x; i < NB; i += 256)
        cur[i] = hist[i] ? atomicAdd(&bucket_cursor[i], hist[i]) : 0;
    __syncthreads();
    for (int e = base + threadIdx.x; e < end; e += 256) {
        int d = dst[e];
        int pos = atomicAdd(&cur[d >> 8], 1);
        binned[pos] = make_int2(src[e], d);
    }
}

__global__ __launch_bounds__(256) void k_bucket(const int2* __restrict__ binned,
                                                const int* __restrict__ bucket_base, int N,
                                                int* __restrict__ rowptr,
                                                float* __restrict__ dinv,
                                                int* __restrict__ csr_src) {
    __shared__ int cnt[256];
    __shared__ int sh[256];
    __shared__ int cur[256];
    int b = blockIdx.x;
    int t = threadIdx.x;
    int node0 = b << 8;
    int lo = bucket_base[b], hi = bucket_base[b + 1];
    cnt[t] = 0;
    __syncthreads();
    for (int p = lo + t; p < hi; p += 256) {
        int2 pr = binned[p];
        atomicAdd(&cnt[pr.y & 255], 1);
    }
    __syncthreads();
    int v = cnt[t];
    sh[t] = v;
    __syncthreads();
    for (int off = 1; off < 256; off <<= 1) {
        int y = (t >= off) ? sh[t - off] : 0;
        __syncthreads();
        sh[t] += y;
        __syncthreads();
    }
    int gbase = lo + (sh[t] - v);
    int node = node0 + t;
    if (node < N) {
        rowptr[node] = gbase;
        dinv[node] = rsqrtf((float)v + 1.0f);   // deg = in-degree + self-loop
    }
    cur[t] = gbase;
    __syncthreads();
    for (int p = lo + t; p < hi; p += 256) {
        int2 pr = binned[p];
        int pos = atomicAdd(&cur[pr.y & 255], 1);
        csr_src[pos] = pr.x;
    }
}

// ---------------- BN params ----------------

__global__ void k_bnparam(const float* __restrict__ sp, const float* __restrict__ g,
                          const float* __restrict__ be, float* __restrict__ scale,
                          float* __restrict__ shift, float invN) {
    int j = threadIdx.x;  // 128 threads
    float s = 0.f, q = 0.f;
#pragma unroll
    for (int w = 0; w < 32; ++w) {
        s += sp[w * 128 + j];
        q += sp[32 * 128 + w * 128 + j];
    }
    float m = s * invN;
    float var = q * invN - m * m;
    float r = rsqrtf(var + BN_EPS);
    float sc = g[j] * r;
    scale[j] = sc;
    shift[j] = be[j] - m * sc;
}

// ---------------- GEMM: Hout[N,M](bf16) = f(X)[N,128] @ W[128,M] ----------------
// MODE 0: X fp32, f = identity
// MODE 1: X bf16, f = relu(X*scale+shift), writes f(X) to x1buf (bf16)
// MODE 2: X bf16, f = relu(X*scale+shift) + bf16(x1buf)
// XsT swizzle: r ^ ((k>>3)&7)<<2 (block-of-4 preserving) to break bank conflicts.

template<int M, int ROWS, int MODE>
__global__ __launch_bounds__(256) void k_gemm(const void* __restrict__ Xv,
                                              const float* __restrict__ W,
                                              ushort_t* __restrict__ Hout, int N,
                                              const float* __restrict__ scale,
                                              const float* __restrict__ shift,
                                              ushort_t* __restrict__ x1buf) {
    __shared__ float Ws[128 * M];
    __shared__ float XsT[128 * ROWS];
    constexpr int CG = M / 4;
    constexpr int RG = 256 / CG;
    static_assert(ROWS / RG == 4, "4 rows per thread");

    int t = threadIdx.x;
    int r0b = blockIdx.x * ROWS;

    for (int i4 = t; i4 < 32 * M; i4 += 256)
        ((float4*)Ws)[i4] = ((const float4*)W)[i4];

    if constexpr (MODE == 0) {
        const float* X = (const float*)Xv;
        for (int idx = t; idx < ROWS * 32; idx += 256) {
            int r = idx >> 5, kq = idx & 31;
            float4 v = {0.f, 0.f, 0.f, 0.f};
            int row = r0b + r;
            if (row < N) v = ((const float4*)(X + (size_t)row * 128))[kq];
            float vv[4] = {v.x, v.y, v.z, v.w};
#pragma unroll
            for (int c = 0; c < 4; ++c) {
                int k = 4 * kq + c;
                XsT[k * ROWS + (r ^ (((k >> 3) & 7) << 2))] = vv[c];
            }
        }
    } else {
        const ushort_t* X = (const ushort_t*)Xv;
        for (int idx = t; idx < ROWS * 16; idx += 256) {
            int r = idx >> 4, ko = idx & 15;
            int row = r0b + r;
            float v[8] = {0.f, 0.f, 0.f, 0.f, 0.f, 0.f, 0.f, 0.f};
            if (row < N) {
                uint4 raw = *(const uint4*)&X[(size_t)row * 128 + ko * 8];
                cvt2(raw.x, v[0], v[1]); cvt2(raw.y, v[2], v[3]);
                cvt2(raw.z, v[4], v[5]); cvt2(raw.w, v[6], v[7]);
                float4 sc0 = *(const float4*)&scale[ko * 8];
                float4 sc1 = *(const float4*)&scale[ko * 8 + 4];
                float4 sh0 = *(const float4*)&shift[ko * 8];
                float4 sh1 = *(const float4*)&shift[ko * 8 + 4];
                v[0] = fmaxf(v[0] * sc0.x + sh0.x, 0.f);
                v[1] = fmaxf(v[1] * sc0.y + sh0.y, 0.f);
                v[2] = fmaxf(v[2] * sc0.z + sh0.z, 0.f);
                v[3] = fmaxf(v[3] * sc0.w + sh0.w, 0.f);
                v[4] = fmaxf(v[4] * sc1.x + sh1.x, 0.f);
                v[5] = fmaxf(v[5] * sc1.y + sh1.y, 0.f);
                v[6] = fmaxf(v[6] * sc1.z + sh1.z, 0.f);
                v[7] = fmaxf(v[7] * sc1.w + sh1.w, 0.f);
                if constexpr (MODE == 1) {
                    uint4 po;
                    po.x = pack2(v[0], v[1]); po.y = pack2(v[2], v[3]);
                    po.z = pack2(v[4], v[5]); po.w = pack2(v[6], v[7]);
                    *(uint4*)&x1buf[(size_t)row * 128 + ko * 8] = po;
                } else {
                    uint4 s4 = *(const uint4*)&x1buf[(size_t)row * 128 + ko * 8];
                    float lo, hi;
                    cvt2(s4.x, lo, hi); v[0] += lo; v[1] += hi;
                    cvt2(s4.y, lo, hi); v[2] += lo; v[3] += hi;
                    cvt2(s4.z, lo, hi); v[4] += lo; v[5] += hi;
                    cvt2(s4.w, lo, hi); v[6] += lo; v[7] += hi;
                }
            }
#pragma unroll
            for (int c = 0; c < 8; ++c) {
                int k = ko * 8 + c;
                XsT[k * ROWS + (r ^ (((k >> 3) & 7) << 2))] = v[c];
            }
        }
    }
    __syncthreads();

    int c = t % CG, rg = t / CG;
    int j0 = c * 4, r0 = rg * 4;
    float4 a0 = {0,0,0,0}, a1 = {0,0,0,0}, a2 = {0,0,0,0}, a3 = {0,0,0,0};

#pragma unroll 8
    for (int k = 0; k < 128; ++k) {
        int rsw = r0 ^ (((k >> 3) & 7) << 2);
        float4 wv = *(const float4*)&Ws[k * M + j0];
        float4 xv = *(const float4*)&XsT[k * ROWS + rsw];
        a0.x += xv.x * wv.x; a0.y += xv.x * wv.y; a0.z += xv.x * wv.z; a0.w += xv.x * wv.w;
        a1.x += xv.y * wv.x; a1.y += xv.y * wv.y; a1.z += xv.y * wv.z; a1.w += xv.y * wv.w;
        a2.x += xv.z * wv.x; a2.y += xv.z * wv.y; a2.z += xv.z * wv.z; a2.w += xv.z * wv.w;
        a3.x += xv.w * wv.x; a3.y += xv.w * wv.y; a3.z += xv.w * wv.z; a3.w += xv.w * wv.w;
    }

    float4 accs[4] = {a0, a1, a2, a3};
#pragma unroll
    for (int i = 0; i < 4; ++i) {
        int row = r0b + r0 + i;
        // rows within the r0..r0+3 block are NOT swizzled in the accumulator
        // (swizzle applies to LDS addresses only); accs[i] corresponds to r0+i.
        if (row < N) {
            ushort4 o;
            o.x = bf16rne(accs[i].x); o.y = bf16rne(accs[i].y);
            o.z = bf16rne(accs[i].z); o.w = bf16rne(accs[i].w);
            *(ushort4*)&Hout[(size_t)row * M + j0] = o;
        }
    }
}

// ---------------- Aggregation (bf16 gather, fp32 accumulate) ----------------
// out = (sum_e dinv[src_e]*h[src_e] + h[i]*di) * di + bias
// BF16OUT: packed bf16 output (full-line stores). Else fp32 via LDS transpose.

template<int M, bool STATS, bool BF16OUT>
__global__ __launch_bounds__(256) void k_agg(const ushort_t* __restrict__ Hm,
                      const int* __restrict__ rowptr,
                      const int* __restrict__ csr_src, const float* __restrict__ dinv,
                      const float* __restrict__ bias, void* __restrict__ Out, int N,
                      float* __restrict__ spread) {
    constexpr int TPN = M / 8;           // threads per node
    constexpr int NPB = 256 / TPN;       // nodes per block
    int li = threadIdx.x / TPN;
    int lane = threadIdx.x % TPN;
    int i = blockIdx.x * NPB + li;
    bool valid = (i < N);
    int j0 = lane * 8;

    float o[8] = {0.f, 0.f, 0.f, 0.f, 0.f, 0.f, 0.f, 0.f};

    if (valid) {
        int p = rowptr[i], p1 = rowptr[i + 1];
        for (; p + 3 < p1; p += 4) {
            int s0 = csr_src[p + 0];
            int s1 = csr_src[p + 1];
            int s2 = csr_src[p + 2];
            int s3 = csr_src[p + 3];
            float c0 = dinv[s0], c1 = dinv[s1], c2 = dinv[s2], c3 = dinv[s3];
            uint4 g0 = *(const uint4*)&Hm[(size_t)s0 * M + j0];
            uint4 g1 = *(const uint4*)&Hm[(size_t)s1 * M + j0];
            uint4 g2 = *(const uint4*)&Hm[(size_t)s2 * M + j0];
            uint4 g3 = *(const uint4*)&Hm[(size_t)s3 * M + j0];
            float lo, hi;
            cvt2(g0.x, lo, hi); o[0] += lo * c0; o[1] += hi * c0;
            cvt2(g0.y, lo, hi); o[2] += lo * c0; o[3] += hi * c0;
            cvt2(g0.z, lo, hi); o[4] += lo * c0; o[5] += hi * c0;
            cvt2(g0.w, lo, hi); o[6] += lo * c0; o[7] += hi * c0;
            cvt2(g1.x, lo, hi); o[0] += lo * c1; o[1] += hi * c1;
            cvt2(g1.y, lo, hi); o[2] += lo * c1; o[3] += hi * c1;
            cvt2(g1.z, lo, hi); o[4] += lo * c1; o[5] += hi * c1;
            cvt2(g1.w, lo, hi); o[6] += lo * c1; o[7] += hi * c1;
            cvt2(g2.x, lo, hi); o[0] += lo * c2; o[1] += hi * c2;
            cvt2(g2.y, lo, hi); o[2] += lo * c2; o[3] += hi * c2;
            cvt2(g2.z, lo, hi); o[4] += lo * c2; o[5] += hi * c2;
            cvt2(g2.w, lo, hi); o[6] += lo * c2; o[7] += hi * c2;
            cvt2(g3.x, lo, hi); o[0] += lo * c3; o[1] += hi * c3;
            cvt2(g3.y, lo, hi); o[2] += lo * c3; o[3] += hi * c3;
            cvt2(g3.z, lo, hi); o[4] += lo * c3; o[5] += hi * c3;
            cvt2(g3.w, lo, hi); o[6] += lo * c3; o[7] += hi * c3;
        }
        for (; p < p1; ++p) {
            int s = csr_src[p];
            float cf = dinv[s];
            uint4 g = *(const uint4*)&Hm[(size_t)s * M + j0];
            float lo, hi;
            cvt2(g.x, lo, hi); o[0] += lo * cf; o[1] += hi * cf;
            cvt2(g.y, lo, hi); o[2] += lo * cf; o[3] += hi * cf;
            cvt2(g.z, lo, hi); o[4] += lo * cf; o[5] += hi * cf;
            cvt2(g.w, lo, hi); o[6] += lo * cf; o[7] += hi * cf;
        }

        float di = dinv[i];
        uint4 hs = *(const uint4*)&Hm[(size_t)i * M + j0];
        float lo, hi;
        cvt2(hs.x, lo, hi); o[0] += lo * di; o[1] += hi * di;
        cvt2(hs.y, lo, hi); o[2] += lo * di; o[3] += hi * di;
        cvt2(hs.z, lo, hi); o[4] += lo * di; o[5] += hi * di;
        cvt2(hs.w, lo, hi); o[6] += lo * di; o[7] += hi * di;

        float4 bv0 = *(const float4*)&bias[j0];
        float4 bv1 = *(const float4*)&bias[j0 + 4];
        o[0] = o[0] * di + bv0.x; o[1] = o[1] * di + bv0.y;
        o[2] = o[2] * di + bv0.z; o[3] = o[3] * di + bv0.w;
        o[4] = o[4] * di + bv1.x; o[5] = o[5] * di + bv1.y;
        o[6] = o[6] * di + bv1.z; o[7] = o[7] * di + bv1.w;
    }

    if constexpr (STATS) {
        float st[16];
#pragma unroll
        for (int k = 0; k < 8; ++k) { st[k] = o[k]; st[8 + k] = o[k] * o[k]; }
#pragma unroll
        for (int k = 0; k < 16; ++k) {
            st[k] += __shfl_xor(st[k], 16);
            st[k] += __shfl_xor(st[k], 32);
        }
        __shared__ float red[4][16][16];
        int wv = threadIdx.x >> 6;
        int ln = threadIdx.x & 63;
        if (ln < 16) {
#pragma unroll
            for (int k = 0; k < 16; ++k) red[wv][ln][k] = st[k];
        }
        __syncthreads();
        if (threadIdx.x < 16) {
            int cg = threadIdx.x;
            int w = (blockIdx.x & 31);
#pragma unroll
            for (int k = 0; k < 16; ++k) {
                float s = red[0][cg][k] + red[1][cg][k] + red[2][cg][k] + red[3][cg][k];
                int j = cg * 8 + (k & 7);
                float* dst = (k < 8) ? &spread[w * 128 + j]
                                     : &spread[32 * 128 + w * 128 + j];
                atomicAdd(dst, s);
            }
        }
    }

    if constexpr (BF16OUT) {
        if (valid) {
            uint4 po;
            po.x = pack2(o[0], o[1]); po.y = pack2(o[2], o[3]);
            po.z = pack2(o[4], o[5]); po.w = pack2(o[6], o[7]);
            *(uint4*)&((ushort_t*)Out)[(size_t)i * M + j0] = po;
        }
    } else {
        // fp32 out, full-line stores via LDS transpose staging
        __shared__ float outs[NPB][M + 4];
#pragma unroll
        for (int cc = 0; cc < 8; ++cc) outs[li][lane * 8 + cc] = o[cc];
        __syncthreads();
        float* Of = (float*)Out;
        int i0 = blockIdx.x * NPB;
        constexpr int Q = M / 4;
        for (int f = threadIdx.x; f < NPB * Q; f += 256) {
            int node = f / Q;
            int q = f % Q;
            if (i0 + node < N)
                *(float4*)&Of[(size_t)(i0 + node) * M + q * 4] = *(float4*)&outs[node][q * 4];
        }
    }
}

// ---------------- launch ----------------

extern "C" void kernel_launch(void* const* d_in, const int* in_sizes, int n_in,
                              void* d_out, int out_size, void* d_ws, size_t ws_size,
                              hipStream_t stream) {
    const float* x   = (const float*)d_in[0];
    const int*   ei  = (const int*)d_in[1];
    const float* W1  = (const float*)d_in[2];
    const float* b1  = (const float*)d_in[3];
    const float* g1  = (const float*)d_in[4];
    const float* be1 = (const float*)d_in[5];
    const float* W2  = (const float*)d_in[6];
    const float* b2  = (const float*)d_in[7];
    const float* g2  = (const float*)d_in[8];
    const float* be2 = (const float*)d_in[9];
    const float* W3  = (const float*)d_in[10];
    const float* b3  = (const float*)d_in[11];

    int N = in_sizes[0] / 128;
    int E = in_sizes[1] / 2;
    const int* srcp = ei;
    const int* dstp = ei + E;
    int NB = (N + 255) >> 8;

    char* ws = (char*)d_ws;
    size_t off = 0;
    auto alloc = [&](size_t bytes) {
        void* p = ws + off;
        off += (bytes + 255) & ~(size_t)255;
        return p;
    };

    int*   rowptr   = (int*)alloc(((size_t)N + 1) * 4);
    int*   csr_src  = (int*)alloc((size_t)E * 4);
    float* dinv     = (float*)alloc((size_t)N * 4);
    int*   bucket_counts = (int*)alloc(512 * 4);
    int*   bucket_base   = (int*)alloc(513 * 4);
    int*   bucket_cursor = (int*)alloc(512 * 4);
    float* spreadA  = (float*)alloc(2 * 32 * 128 * 4);
    float* spreadB  = (float*)alloc(2 * 32 * 128 * 4);
    float* scale1   = (float*)alloc(128 * 4);
    float* shift1   = (float*)alloc(128 * 4);
    float* scale2   = (float*)alloc(128 * 4);
    float* shift2   = (float*)alloc(128 * 4);
    ushort_t* hbuf  = (ushort_t*)alloc((size_t)N * 128 * 2);  // bf16 h-table
    ushort_t* x1bf  = (ushort_t*)alloc((size_t)N * 128 * 2);  // bf16 x1 (skip)
    ushort_t* abuf1 = (ushort_t*)alloc((size_t)N * 128 * 2);  // bf16 a1 (agg1 out)
    ushort_t* abuf2 = (ushort_t*)alloc((size_t)N * 128 * 2);  // bf16 a2 (agg2 out)
    int2*  binned = (int2*)abuf1;   // alias: binned dead before abuf1 first written

    float invN = 1.0f / (float)N;
    int nbE = (E + BIN_CHUNK - 1) / BIN_CHUNK;

    // CSR build (2-pass counting sort)
    hipMemsetAsync(bucket_counts, 0, 512 * 4, stream);
    k_binhist<<<nbE, 256, 0, stream>>>(dstp, E, NB, bucket_counts);
    k_bucketscan<<<1, 512, 0, stream>>>(bucket_counts, NB, N, E,
                                        bucket_base, bucket_cursor, rowptr);
    k_bin<<<nbE, 256, 0, stream>>>(srcp, dstp, E, NB, bucket_cursor, binned);
    k_bucket<<<NB, 256, 0, stream>>>(binned, bucket_base, N, rowptr, dinv, csr_src);
    hipMemsetAsync(spreadA, 0, 2 * 32 * 128 * 4, stream);
    hipMemsetAsync(spreadB, 0, 2 * 32 * 128 * 4, stream);

    // layer 1: h = x@W1 ; a1 = agg(h) + stats (a1 stored bf16)
    k_gemm<128, 32, 0><<<(N + 31) / 32, 256, 0, stream>>>(x, W1, hbuf, N,
                                                          nullptr, nullptr, nullptr);
    k_agg<128, true, true><<<(N + 15) / 16, 256, 0, stream>>>(hbuf, rowptr, csr_src, dinv,
                                                              b1, abuf1, N, spreadA);
    k_bnparam<<<1, 128, 0, stream>>>(spreadA, g1, be1, scale1, shift1, invN);

    // layer 2: h = relu(bn1(a1))@W2 (x1 written bf16) ; a2 = agg(h) + stats
    k_gemm<128, 32, 1><<<(N + 31) / 32, 256, 0, stream>>>(abuf1, W2, hbuf, N,
                                                          scale1, shift1, x1bf);
    k_agg<128, true, true><<<(N + 15) / 16, 256, 0, stream>>>(hbuf, rowptr, csr_src, dinv,
                                                              b2, abuf2, N, spreadB);
    k_bnparam<<<1, 128, 0, stream>>>(spreadB, g2, be2, scale2, shift2, invN);

    // layer 3: h = (relu(bn2(a2)) + x1)@W3 ; out = agg(h) (fp32, LDS-staged stores)
    k_gemm<64, 64, 2><<<(N + 63) / 64, 256, 0, stream>>>(abuf2, W3, hbuf, N,
                                                         scale2, shift2, x1bf);
    k_agg<64, false, false><<<(N + 31) / 32, 256, 0, stream>>>(hbuf, rowptr, csr_src, dinv,
                                                               b3, d_out, N, nullptr);
}